// Round 5
// baseline (343.738 us; speedup 1.0000x reference)
//
#include <hip/hip_runtime.h>
#include <hip/hip_bf16.h>

// ROUND 21. r20 WIN (331.0). Top = agg_csr x2 @63us, FETCH 84.5 MB,
// 1.58 TB/s: bytes-bound at L2-fill (~200 GB/s/XCD). kv-gather miss ~62 MB
// is structural (12.8 MB set vs 4 MiB/XCD L2). Byte-reduction round:
//  1) s stream f32 -> bf16: -6.4 MB per agg read, -6.4 MB per gemm write
//     (x2 layers = -25.6 MB). Precision +<=0.001 abs (watch absmax).
//  2) gemm1 reads x f32 directly, cvt to bf16 in-register (MfmaUtil 1.6% ->
//     headroom). Kills xb round-trip: 51.2 -> 25.6 MB, prep shrinks ~2/3.
//     A-row index clamped (x has no pad rows).
// Predict: agg 63 -> ~58 each, total 331 -> ~300-310. If absmax fails,
// revert (1).

#define N_NODES 50000
#define N_EDGES 800000
#define NB_SCAN 196   // ceil(50000/256)
#define NPAD    50048 // 782*64
#define GEMM_BLKS 782
#define EPB 2048       // edges per scatter block
#define SCAT_BLKS 391  // ceil(800000/2048)
#define NBK 196        // buckets of 256 nodes (dst>>8)
#define CURSTRIDE 16   // one cursor per 64B line

using bf16 = __hip_bfloat16;
typedef __attribute__((ext_vector_type(8))) short bf16x8;
typedef __attribute__((ext_vector_type(4))) float f32x4;

__device__ __forceinline__ float b2f(unsigned short u) {
    unsigned int x = ((unsigned int)u) << 16;
    return __builtin_bit_cast(float, x);
}
__device__ __forceinline__ short f2b(float f) {
    return (short)__builtin_bit_cast(unsigned short, __float2bfloat16(f));
}

struct WPtrs { const float* p[8]; };

// ---------------- fused prep: conv_w / hist (x-conv removed) ----------------
__global__ __launch_bounds__(256) void prep(WPtrs wp, bf16* __restrict__ wb,
                                            const int* __restrict__ ei,
                                            int* __restrict__ deg) {
    const int gs = gridDim.x * 256;
    const int t0 = blockIdx.x * 256 + threadIdx.x;
    if (blockIdx.y == 0) {
        for (int e = t0; e < N_EDGES; e += gs)
            atomicAdd(&deg[ei[N_EDGES + e]], 1);
    } else {
        for (int i = t0; i < 49152; i += gs) {
            int y, o;
            if (i < 32768) { y = i >> 13; o = i & 8191; }
            else { y = 4 + ((i - 32768) >> 12); o = (i - 32768) & 4095; }
            wb[i] = __float2bfloat16(wp.p[y][o]);
        }
    }
}

// ---------------- MFMA GEMM body (64-row tile, 4 weight mats) ----------------
// AT = float: read f32 A (x input), cvt to bf16 in-register, row-clamped.
// AT = bf16 : read bf16 A (hb), rows padded to NPAD, no clamp needed.
template <int K, typename AT>
__device__ __forceinline__ void gemm_body(
    int blk, int tid,
    const AT* __restrict__ A, const bf16* __restrict__ wb,
    const float* __restrict__ bq, const float* __restrict__ bk,
    const float* __restrict__ bv, const float* __restrict__ bs,
    bf16* __restrict__ qb, bf16* __restrict__ kvb, bf16* __restrict__ sb) {
    const int wave = tid >> 6;
    const int lane = tid & 63;
    const int row0 = blk * 64;
    const int m  = lane & 15;
    const int kg = lane >> 4;
    const bf16* W = wb + (size_t)wave * 64 * K;

    f32x4 acc[4][4];
#pragma unroll
    for (int i = 0; i < 4; ++i)
#pragma unroll
        for (int j = 0; j < 4; ++j) acc[i][j] = (f32x4){0.f, 0.f, 0.f, 0.f};

#pragma unroll
    for (int k0 = 0; k0 < K; k0 += 32) {
        bf16x8 a[4], b[4];
#pragma unroll
        for (int i = 0; i < 4; ++i) {
            if constexpr (__hip_internal::is_same<AT, float>::value) {
                int r = row0 + i * 16 + m;
                if (r >= N_NODES) r = N_NODES - 1;  // x has no pad rows
                const float* ap = A + (size_t)r * K + k0 + kg * 8;
                f32x4 lo = *(const f32x4*)ap;
                f32x4 hi = *(const f32x4*)(ap + 4);
#pragma unroll
                for (int q = 0; q < 4; ++q) {
                    a[i][q]     = f2b(lo[q]);
                    a[i][q + 4] = f2b(hi[q]);
                }
            } else {
                a[i] = *(const bf16x8*)(A + (size_t)(row0 + i * 16 + m) * K + k0 + kg * 8);
            }
        }
#pragma unroll
        for (int j = 0; j < 4; ++j)
            b[j] = *(const bf16x8*)(W + (size_t)(j * 16 + m) * K + k0 + kg * 8);
#pragma unroll
        for (int i = 0; i < 4; ++i)
#pragma unroll
            for (int j = 0; j < 4; ++j)
                acc[i][j] = __builtin_amdgcn_mfma_f32_16x16x32_bf16(a[i], b[j], acc[i][j], 0, 0, 0);
    }

    const int crow = (lane >> 4) * 4;
    const int ccol = lane & 15;
    const float* B = (wave == 0) ? bq : (wave == 1) ? bk : (wave == 2) ? bv : bs;
    float bias[4];
#pragma unroll
    for (int j = 0; j < 4; ++j) bias[j] = B[j * 16 + ccol];

#pragma unroll
    for (int i = 0; i < 4; ++i)
#pragma unroll
        for (int r = 0; r < 4; ++r) {
            int gr = row0 + i * 16 + crow + r;
            if (gr >= N_NODES) continue;
#pragma unroll
            for (int j = 0; j < 4; ++j) {
                float val = acc[i][j][r] + bias[j];
                size_t idx = (size_t)gr * 64 + j * 16 + ccol;
                if (wave == 0) qb[idx] = __float2bfloat16(val);
                else if (wave == 1) kvb[idx * 2] = __float2bfloat16(val);
                else if (wave == 2) kvb[idx * 2 + 1] = __float2bfloat16(val);
                else sb[idx] = __float2bfloat16(val);
            }
        }
}

// layer-1 GEMM (f32 x input) + pass-A LDS-binned scatter fused.
__global__ __launch_bounds__(256) void gemm1_scatter(
    const float* __restrict__ A, const bf16* __restrict__ wb,
    const float* __restrict__ bq, const float* __restrict__ bk,
    const float* __restrict__ bv, const float* __restrict__ bs,
    bf16* __restrict__ qb, bf16* __restrict__ kvb, bf16* __restrict__ sb,
    const int* __restrict__ ei, const int* __restrict__ off,
    int* __restrict__ gcur, unsigned int* __restrict__ pairs) {
    __shared__ int hist[256];
    __shared__ int sm[256];
    __shared__ int obs[NBK];
    __shared__ unsigned int stage[EPB];

    if (blockIdx.x < GEMM_BLKS) {
        gemm_body<128, float>(blockIdx.x, threadIdx.x, A, wb, bq, bk, bv, bs, qb, kvb, sb);
        return;
    }
    const int t = threadIdx.x;
    const int e0 = (blockIdx.x - GEMM_BLKS) * EPB;
    hist[t] = 0;
    __syncthreads();

    // per-edge: bucket + within-bucket rank via LDS atomics
    unsigned int pk[8];
    int bb[8], rr[8];
#pragma unroll
    for (int u = 0; u < 8; ++u) {
        const int e = e0 + u * 256 + t;
        if (e < N_EDGES) {
            int d  = ei[N_EDGES + e];
            int sv = ei[e];
            pk[u] = ((unsigned int)d << 16) | (unsigned int)sv;
            bb[u] = d >> 8;
            rr[u] = atomicAdd(&hist[bb[u]], 1);
        } else {
            bb[u] = -1;
        }
    }
    __syncthreads();

    // block-wide inclusive scan of hist (256 entries, Hillis-Steele)
    int hv = hist[t];
    sm[t] = hv;
    __syncthreads();
    for (int st = 1; st < 256; st <<= 1) {
        int tmp = (t >= st) ? sm[t - st] : 0;
        __syncthreads();
        sm[t] += tmp;
        __syncthreads();
    }
    const int total = sm[255];

    // one global reservation per non-empty bucket
    if (t < NBK && hv > 0) {
        int g = atomicAdd(&gcur[t * CURSTRIDE], hv);
        obs[t] = off[t << 8] + g - (sm[t] - hv);  // global base minus local run start
    }
    __syncthreads();

    // bin into LDS staging (bucket-sorted)
#pragma unroll
    for (int u = 0; u < 8; ++u)
        if (bb[u] >= 0) stage[(sm[bb[u]] - hist[bb[u]]) + rr[u]] = pk[u];
    __syncthreads();

    // copy-out: consecutive j within a bucket run -> contiguous global stores
    for (int j = t; j < total; j += 256) {
        unsigned int pr = stage[j];
        int b = pr >> 24;  // dst>>8
        pairs[obs[b] + j] = pr;
    }
}

// Pass B: one block per bucket (256 nodes). off-window in LDS, LDS-rank,
// dense stores into the bucket's contiguous csr region.
__global__ __launch_bounds__(256) void passB(const int* __restrict__ off,
                                             const unsigned int* __restrict__ pairs,
                                             int* __restrict__ csr) {
    __shared__ int lcnt[256];
    __shared__ int loff[256];
    const int b = blockIdx.x;
    const int n0 = b << 8;
    const int nend = (n0 + 256 < N_NODES) ? n0 + 256 : N_NODES;
    lcnt[threadIdx.x] = 0;
    if (n0 + threadIdx.x < nend) loff[threadIdx.x] = off[n0 + threadIdx.x];
    const int p0 = off[n0];
    const int p1 = off[nend];
    __syncthreads();
    for (int j = p0 + threadIdx.x; j < p1; j += 256) {
        unsigned int pr = pairs[j];
        int d  = (int)(pr >> 16);
        int sv = (int)(pr & 0xffffu);
        int r = atomicAdd(&lcnt[d - n0], 1);
        csr[loff[d - n0] + r] = sv;
    }
}

__global__ __launch_bounds__(256) void gemm2(
    const bf16* __restrict__ A, const bf16* __restrict__ wb,
    const float* __restrict__ bq, const float* __restrict__ bk,
    const float* __restrict__ bv, const float* __restrict__ bs,
    bf16* __restrict__ qb, bf16* __restrict__ kvb, bf16* __restrict__ sb) {
    gemm_body<64, bf16>(blockIdx.x, threadIdx.x, A, wb, bq, bk, bv, bs, qb, kvb, sb);
}

// ---------------- CSR scan ----------------
__global__ __launch_bounds__(256) void scan1(const int* __restrict__ deg,
                                             int* __restrict__ off,
                                             int* __restrict__ bsum) {
    __shared__ int sm[256];
    int i = blockIdx.x * 256 + threadIdx.x;
    int v = (i < N_NODES) ? deg[i] : 0;
    sm[threadIdx.x] = v;
    __syncthreads();
    for (int st = 1; st < 256; st <<= 1) {
        int t = (threadIdx.x >= (unsigned)st) ? sm[threadIdx.x - st] : 0;
        __syncthreads();
        sm[threadIdx.x] += t;
        __syncthreads();
    }
    if (i < N_NODES) off[i] = sm[threadIdx.x] - v;
    if (threadIdx.x == 255) bsum[blockIdx.x] = sm[255];
}

__global__ __launch_bounds__(256) void scan2(const int* __restrict__ bsum,
                                             int* __restrict__ boff) {
    __shared__ int sm[256];
    int b = threadIdx.x;
    int v = (b < NB_SCAN) ? bsum[b] : 0;
    sm[b] = v;
    __syncthreads();
    for (int st = 1; st < 256; st <<= 1) {
        int t = (b >= st) ? sm[b - st] : 0;
        __syncthreads();
        sm[b] += t;
        __syncthreads();
    }
    if (b < NB_SCAN) boff[b] = sm[b] - v;
    if (b == 255) boff[NB_SCAN] = sm[255];
}

__global__ __launch_bounds__(256) void scan3(int* __restrict__ off,
                                             const int* __restrict__ boff,
                                             int* __restrict__ gcur) {
    int i = blockIdx.x * 256 + threadIdx.x;
    if (i < N_NODES) off[i] = off[i] + boff[blockIdx.x];
    if (i == 0) off[N_NODES] = boff[NB_SCAN];
    if (i < NBK * CURSTRIDE) gcur[i] = 0;
}

// ------------- Aggregation: wave/node, nt streaming, unroll 16 -------------
template <int H, bool RELU, typename OT>  // D = 64/H
__global__ __launch_bounds__(256) void agg_csr(const int* __restrict__ off,
                                               const int* __restrict__ csr_src,
                                               const bf16* __restrict__ qb,
                                               const unsigned int* __restrict__ kvu,
                                               const bf16* __restrict__ sb,
                                               OT* __restrict__ out) {
    const int D = 64 / H;
    const float scale = (D == 16) ? 0.25f : 0.125f;
    const int lane = threadIdx.x & 63;
    const int n = (blockIdx.x * 256 + threadIdx.x) >> 6;
    if (n >= N_NODES) return;

    const float qv = b2f(__builtin_nontemporal_load(
        (const unsigned short*)qb + (size_t)n * 64 + lane));
    float acc = 0.f, dsum = 0.f;
    int j = off[n];
    const int j1 = off[n + 1];

    for (; j + 15 < j1; j += 16) {
        unsigned int w[16];
#pragma unroll
        for (int u = 0; u < 16; ++u)
            w[u] = kvu[(size_t)csr_src[j + u] * 64 + lane];
        float p[16];
#pragma unroll
        for (int u = 0; u < 16; ++u) p[u] = qv * b2f((unsigned short)w[u]);
#pragma unroll
        for (int o = 1; o < D; o <<= 1)
#pragma unroll
            for (int u = 0; u < 16; ++u) p[u] += __shfl_xor(p[u], o, 64);
#pragma unroll
        for (int u = 0; u < 16; ++u) {
            float e = __expf(p[u] * scale);
            acc += e * b2f((unsigned short)(w[u] >> 16));
            dsum += e;
        }
    }
    for (; j + 3 < j1; j += 4) {
        unsigned int w[4];
#pragma unroll
        for (int u = 0; u < 4; ++u)
            w[u] = kvu[(size_t)csr_src[j + u] * 64 + lane];
        float p[4];
#pragma unroll
        for (int u = 0; u < 4; ++u) p[u] = qv * b2f((unsigned short)w[u]);
#pragma unroll
        for (int o = 1; o < D; o <<= 1)
#pragma unroll
            for (int u = 0; u < 4; ++u) p[u] += __shfl_xor(p[u], o, 64);
#pragma unroll
        for (int u = 0; u < 4; ++u) {
            float e = __expf(p[u] * scale);
            acc += e * b2f((unsigned short)(w[u] >> 16));
            dsum += e;
        }
    }
    for (; j < j1; ++j) {
        unsigned int w = kvu[(size_t)csr_src[j] * 64 + lane];
        float p = qv * b2f((unsigned short)w);
#pragma unroll
        for (int o = 1; o < D; o <<= 1) p += __shfl_xor(p, o, 64);
        float e = __expf(p * scale);
        acc += e * b2f((unsigned short)(w >> 16));
        dsum += e;
    }
    float a = (dsum != 0.f) ? acc / dsum : 0.f;
    float sk = b2f(__builtin_nontemporal_load(
        (const unsigned short*)sb + (size_t)n * 64 + lane));
    float val = a + sk;
    if (RELU) val = fmaxf(val, 0.f);
    if constexpr (__hip_internal::is_same<OT, bf16>::value)
        out[(size_t)n * 64 + lane] = __float2bfloat16(val);  // hb: re-read by gemm2
    else
        __builtin_nontemporal_store(val, out + (size_t)n * 64 + lane);  // d_out: nt
}

extern "C" void kernel_launch(void* const* d_in, const int* in_sizes, int n_in,
                              void* d_out, int out_size, void* d_ws, size_t ws_size,
                              hipStream_t stream) {
    const float* x  = (const float*)d_in[0];
    const int*   ei = (const int*)d_in[1];
    const float* bq1 = (const float*)d_in[3];
    const float* bk1 = (const float*)d_in[5];
    const float* bv1 = (const float*)d_in[7];
    const float* bs1 = (const float*)d_in[9];
    const float* bq2 = (const float*)d_in[11];
    const float* bk2 = (const float*)d_in[13];
    const float* bv2 = (const float*)d_in[15];
    const float* bs2 = (const float*)d_in[17];

    WPtrs wp;
    wp.p[0] = (const float*)d_in[2];
    wp.p[1] = (const float*)d_in[4];
    wp.p[2] = (const float*)d_in[6];
    wp.p[3] = (const float*)d_in[8];
    wp.p[4] = (const float*)d_in[10];
    wp.p[5] = (const float*)d_in[12];
    wp.p[6] = (const float*)d_in[14];
    wp.p[7] = (const float*)d_in[16];

    const size_t N = N_NODES;
    bf16* hb  = (bf16*)d_ws;                 // NPAD*64
    bf16* qb  = hb + (size_t)NPAD * 64;      // N*64
    bf16* kvb = qb + N * 64;                 // 2*N*64 interleaved
    bf16* wb  = kvb + 2 * N * 64;            // 49152
    bf16* sb  = wb + 49152;                  // N*64 (bf16 now)
    int* deg  = (int*)(sb + N * 64);         // N
    int* off  = deg + N_NODES;               // N+1
    int* gcur = off + N_NODES + 1;           // NBK*CURSTRIDE
    int* bsum = gcur + N_NODES;              // NB_SCAN
    int* boff = bsum + NB_SCAN;              // NB_SCAN+1
    int* csr  = boff + NB_SCAN + 1;          // E
    unsigned int* pairs = (unsigned int*)(csr + N_EDGES); // E

    const int aggGrid = (N_NODES * 64 + 255) / 256;

    // ---------------- prep + CSR ----------------
    hipMemsetAsync(deg, 0, N_NODES * sizeof(int), stream);
    prep<<<dim3(1024, 2), 256, 0, stream>>>(wp, wb, ei, deg);
    scan1<<<NB_SCAN, 256, 0, stream>>>(deg, off, bsum);
    scan2<<<1, 256, 0, stream>>>(bsum, boff);
    scan3<<<NB_SCAN, 256, 0, stream>>>(off, boff, gcur);

    // ---------------- Layer 1 (gemm on f32 x + pass-A binning fused) --------
    gemm1_scatter<<<GEMM_BLKS + SCAT_BLKS, 256, 0, stream>>>(
        x, wb, bq1, bk1, bv1, bs1, qb, kvb, sb, ei, off, gcur, pairs);
    passB<<<NBK, 256, 0, stream>>>(off, pairs, csr);
    agg_csr<4, true, bf16><<<aggGrid, 256, 0, stream>>>(off, csr, qb,
                                                        (const unsigned int*)kvb, sb, hb);

    // ---------------- Layer 2 ----------------
    gemm2<<<GEMM_BLKS, 256, 0, stream>>>(hb, wb + 32768, bq2, bk2, bv2, bs2,
                                         qb, kvb, sb);
    agg_csr<1, false, float><<<aggGrid, 256, 0, stream>>>(off, csr, qb,
                                                          (const unsigned int*)kvb, sb,
                                                          (float*)d_out);
}

// Round 6
// 330.703 us; speedup vs baseline: 1.0394x; 1.0394x over previous
//
#include <hip/hip_runtime.h>
#include <hip/hip_bf16.h>

// ROUND 22. r21 FAILED (343.7): direct f32-x read put 2x loads + cvt on the
// MFMA dependent chain (gemm1 67->73us, FETCH +6MB, 21% occ) - reverted to
// prep-staged bf16 xb. KEPT sb f32->bf16 (worked: WRITE 72->31.7 MB, agg out
// of top-5; absmax 0.0059 passes).
// Predict: gemm1 back <=60us (FETCH ~10.5MB), agg ~57 each, total ~315-322.
// Next target after this lands: agg kv-gather 62MB L2-miss stream.

#define N_NODES 50000
#define N_EDGES 800000
#define NB_SCAN 196   // ceil(50000/256)
#define NPAD    50048 // 782*64
#define GEMM_BLKS 782
#define EPB 2048       // edges per scatter block
#define SCAT_BLKS 391  // ceil(800000/2048)
#define NBK 196        // buckets of 256 nodes (dst>>8)
#define CURSTRIDE 16   // one cursor per 64B line

using bf16 = __hip_bfloat16;
typedef __attribute__((ext_vector_type(8))) short bf16x8;
typedef __attribute__((ext_vector_type(4))) float f32x4;

__device__ __forceinline__ float b2f(unsigned short u) {
    unsigned int x = ((unsigned int)u) << 16;
    return __builtin_bit_cast(float, x);
}

struct WPtrs { const float* p[8]; };

// ---------------- fused prep: conv_x / conv_w / hist ----------------
__global__ __launch_bounds__(256) void prep(const float* __restrict__ x,
                                            bf16* __restrict__ xb,
                                            WPtrs wp, bf16* __restrict__ wb,
                                            const int* __restrict__ ei,
                                            int* __restrict__ deg) {
    const int gs = gridDim.x * 256;
    const int t0 = blockIdx.x * 256 + threadIdx.x;
    if (blockIdx.y == 0) {
        for (int i = t0; i < N_NODES * 128; i += gs)
            xb[i] = __float2bfloat16(x[i]);
    } else if (blockIdx.y == 1) {
        for (int i = t0; i < 49152; i += gs) {
            int y, o;
            if (i < 32768) { y = i >> 13; o = i & 8191; }
            else { y = 4 + ((i - 32768) >> 12); o = (i - 32768) & 4095; }
            wb[i] = __float2bfloat16(wp.p[y][o]);
        }
    } else {
        for (int e = t0; e < N_EDGES; e += gs)
            atomicAdd(&deg[ei[N_EDGES + e]], 1);
    }
}

// ---------------- MFMA GEMM body (64-row tile, 4 weight mats) ----------------
template <int K>
__device__ __forceinline__ void gemm_body(
    int blk, int tid,
    const bf16* __restrict__ A, const bf16* __restrict__ wb,
    const float* __restrict__ bq, const float* __restrict__ bk,
    const float* __restrict__ bv, const float* __restrict__ bs,
    bf16* __restrict__ qb, bf16* __restrict__ kvb, bf16* __restrict__ sb) {
    const int wave = tid >> 6;
    const int lane = tid & 63;
    const int row0 = blk * 64;
    const int m  = lane & 15;
    const int kg = lane >> 4;
    const bf16* W = wb + (size_t)wave * 64 * K;

    f32x4 acc[4][4];
#pragma unroll
    for (int i = 0; i < 4; ++i)
#pragma unroll
        for (int j = 0; j < 4; ++j) acc[i][j] = (f32x4){0.f, 0.f, 0.f, 0.f};

#pragma unroll
    for (int k0 = 0; k0 < K; k0 += 32) {
        bf16x8 a[4], b[4];
#pragma unroll
        for (int i = 0; i < 4; ++i)
            a[i] = *(const bf16x8*)(A + (size_t)(row0 + i * 16 + m) * K + k0 + kg * 8);
#pragma unroll
        for (int j = 0; j < 4; ++j)
            b[j] = *(const bf16x8*)(W + (size_t)(j * 16 + m) * K + k0 + kg * 8);
#pragma unroll
        for (int i = 0; i < 4; ++i)
#pragma unroll
            for (int j = 0; j < 4; ++j)
                acc[i][j] = __builtin_amdgcn_mfma_f32_16x16x32_bf16(a[i], b[j], acc[i][j], 0, 0, 0);
    }

    const int crow = (lane >> 4) * 4;
    const int ccol = lane & 15;
    const float* B = (wave == 0) ? bq : (wave == 1) ? bk : (wave == 2) ? bv : bs;
    float bias[4];
#pragma unroll
    for (int j = 0; j < 4; ++j) bias[j] = B[j * 16 + ccol];

#pragma unroll
    for (int i = 0; i < 4; ++i)
#pragma unroll
        for (int r = 0; r < 4; ++r) {
            int gr = row0 + i * 16 + crow + r;
            if (gr >= N_NODES) continue;
#pragma unroll
            for (int j = 0; j < 4; ++j) {
                float val = acc[i][j][r] + bias[j];
                size_t idx = (size_t)gr * 64 + j * 16 + ccol;
                if (wave == 0) qb[idx] = __float2bfloat16(val);
                else if (wave == 1) kvb[idx * 2] = __float2bfloat16(val);
                else if (wave == 2) kvb[idx * 2 + 1] = __float2bfloat16(val);
                else sb[idx] = __float2bfloat16(val);
            }
        }
}

// layer-1 GEMM + pass-A LDS-binned scatter fused.
__global__ __launch_bounds__(256) void gemm1_scatter(
    const bf16* __restrict__ A, const bf16* __restrict__ wb,
    const float* __restrict__ bq, const float* __restrict__ bk,
    const float* __restrict__ bv, const float* __restrict__ bs,
    bf16* __restrict__ qb, bf16* __restrict__ kvb, bf16* __restrict__ sb,
    const int* __restrict__ ei, const int* __restrict__ off,
    int* __restrict__ gcur, unsigned int* __restrict__ pairs) {
    __shared__ int hist[256];
    __shared__ int sm[256];
    __shared__ int obs[NBK];
    __shared__ unsigned int stage[EPB];

    if (blockIdx.x < GEMM_BLKS) {
        gemm_body<128>(blockIdx.x, threadIdx.x, A, wb, bq, bk, bv, bs, qb, kvb, sb);
        return;
    }
    const int t = threadIdx.x;
    const int e0 = (blockIdx.x - GEMM_BLKS) * EPB;
    hist[t] = 0;
    __syncthreads();

    // per-edge: bucket + within-bucket rank via LDS atomics
    unsigned int pk[8];
    int bb[8], rr[8];
#pragma unroll
    for (int u = 0; u < 8; ++u) {
        const int e = e0 + u * 256 + t;
        if (e < N_EDGES) {
            int d  = ei[N_EDGES + e];
            int sv = ei[e];
            pk[u] = ((unsigned int)d << 16) | (unsigned int)sv;
            bb[u] = d >> 8;
            rr[u] = atomicAdd(&hist[bb[u]], 1);
        } else {
            bb[u] = -1;
        }
    }
    __syncthreads();

    // block-wide inclusive scan of hist (256 entries, Hillis-Steele)
    int hv = hist[t];
    sm[t] = hv;
    __syncthreads();
    for (int st = 1; st < 256; st <<= 1) {
        int tmp = (t >= st) ? sm[t - st] : 0;
        __syncthreads();
        sm[t] += tmp;
        __syncthreads();
    }
    const int total = sm[255];

    // one global reservation per non-empty bucket
    if (t < NBK && hv > 0) {
        int g = atomicAdd(&gcur[t * CURSTRIDE], hv);
        obs[t] = off[t << 8] + g - (sm[t] - hv);  // global base minus local run start
    }
    __syncthreads();

    // bin into LDS staging (bucket-sorted)
#pragma unroll
    for (int u = 0; u < 8; ++u)
        if (bb[u] >= 0) stage[(sm[bb[u]] - hist[bb[u]]) + rr[u]] = pk[u];
    __syncthreads();

    // copy-out: consecutive j within a bucket run -> contiguous global stores
    for (int j = t; j < total; j += 256) {
        unsigned int pr = stage[j];
        int b = pr >> 24;  // dst>>8
        pairs[obs[b] + j] = pr;
    }
}

// Pass B: one block per bucket (256 nodes). off-window in LDS, LDS-rank,
// dense stores into the bucket's contiguous csr region.
__global__ __launch_bounds__(256) void passB(const int* __restrict__ off,
                                             const unsigned int* __restrict__ pairs,
                                             int* __restrict__ csr) {
    __shared__ int lcnt[256];
    __shared__ int loff[256];
    const int b = blockIdx.x;
    const int n0 = b << 8;
    const int nend = (n0 + 256 < N_NODES) ? n0 + 256 : N_NODES;
    lcnt[threadIdx.x] = 0;
    if (n0 + threadIdx.x < nend) loff[threadIdx.x] = off[n0 + threadIdx.x];
    const int p0 = off[n0];
    const int p1 = off[nend];
    __syncthreads();
    for (int j = p0 + threadIdx.x; j < p1; j += 256) {
        unsigned int pr = pairs[j];
        int d  = (int)(pr >> 16);
        int sv = (int)(pr & 0xffffu);
        int r = atomicAdd(&lcnt[d - n0], 1);
        csr[loff[d - n0] + r] = sv;
    }
}

__global__ __launch_bounds__(256) void gemm2(
    const bf16* __restrict__ A, const bf16* __restrict__ wb,
    const float* __restrict__ bq, const float* __restrict__ bk,
    const float* __restrict__ bv, const float* __restrict__ bs,
    bf16* __restrict__ qb, bf16* __restrict__ kvb, bf16* __restrict__ sb) {
    gemm_body<64>(blockIdx.x, threadIdx.x, A, wb, bq, bk, bv, bs, qb, kvb, sb);
}

// ---------------- CSR scan ----------------
__global__ __launch_bounds__(256) void scan1(const int* __restrict__ deg,
                                             int* __restrict__ off,
                                             int* __restrict__ bsum) {
    __shared__ int sm[256];
    int i = blockIdx.x * 256 + threadIdx.x;
    int v = (i < N_NODES) ? deg[i] : 0;
    sm[threadIdx.x] = v;
    __syncthreads();
    for (int st = 1; st < 256; st <<= 1) {
        int t = (threadIdx.x >= (unsigned)st) ? sm[threadIdx.x - st] : 0;
        __syncthreads();
        sm[threadIdx.x] += t;
        __syncthreads();
    }
    if (i < N_NODES) off[i] = sm[threadIdx.x] - v;
    if (threadIdx.x == 255) bsum[blockIdx.x] = sm[255];
}

__global__ __launch_bounds__(256) void scan2(const int* __restrict__ bsum,
                                             int* __restrict__ boff) {
    __shared__ int sm[256];
    int b = threadIdx.x;
    int v = (b < NB_SCAN) ? bsum[b] : 0;
    sm[b] = v;
    __syncthreads();
    for (int st = 1; st < 256; st <<= 1) {
        int t = (b >= st) ? sm[b - st] : 0;
        __syncthreads();
        sm[b] += t;
        __syncthreads();
    }
    if (b < NB_SCAN) boff[b] = sm[b] - v;
    if (b == 255) boff[NB_SCAN] = sm[255];
}

__global__ __launch_bounds__(256) void scan3(int* __restrict__ off,
                                             const int* __restrict__ boff,
                                             int* __restrict__ gcur) {
    int i = blockIdx.x * 256 + threadIdx.x;
    if (i < N_NODES) off[i] = off[i] + boff[blockIdx.x];
    if (i == 0) off[N_NODES] = boff[NB_SCAN];
    if (i < NBK * CURSTRIDE) gcur[i] = 0;
}

// ------------- Aggregation: wave/node, nt streaming, unroll 16 -------------
template <int H, bool RELU, typename OT>  // D = 64/H
__global__ __launch_bounds__(256) void agg_csr(const int* __restrict__ off,
                                               const int* __restrict__ csr_src,
                                               const bf16* __restrict__ qb,
                                               const unsigned int* __restrict__ kvu,
                                               const bf16* __restrict__ sb,
                                               OT* __restrict__ out) {
    const int D = 64 / H;
    const float scale = (D == 16) ? 0.25f : 0.125f;
    const int lane = threadIdx.x & 63;
    const int n = (blockIdx.x * 256 + threadIdx.x) >> 6;
    if (n >= N_NODES) return;

    const float qv = b2f(__builtin_nontemporal_load(
        (const unsigned short*)qb + (size_t)n * 64 + lane));
    float acc = 0.f, dsum = 0.f;
    int j = off[n];
    const int j1 = off[n + 1];

    for (; j + 15 < j1; j += 16) {
        unsigned int w[16];
#pragma unroll
        for (int u = 0; u < 16; ++u)
            w[u] = kvu[(size_t)csr_src[j + u] * 64 + lane];
        float p[16];
#pragma unroll
        for (int u = 0; u < 16; ++u) p[u] = qv * b2f((unsigned short)w[u]);
#pragma unroll
        for (int o = 1; o < D; o <<= 1)
#pragma unroll
            for (int u = 0; u < 16; ++u) p[u] += __shfl_xor(p[u], o, 64);
#pragma unroll
        for (int u = 0; u < 16; ++u) {
            float e = __expf(p[u] * scale);
            acc += e * b2f((unsigned short)(w[u] >> 16));
            dsum += e;
        }
    }
    for (; j + 3 < j1; j += 4) {
        unsigned int w[4];
#pragma unroll
        for (int u = 0; u < 4; ++u)
            w[u] = kvu[(size_t)csr_src[j + u] * 64 + lane];
        float p[4];
#pragma unroll
        for (int u = 0; u < 4; ++u) p[u] = qv * b2f((unsigned short)w[u]);
#pragma unroll
        for (int o = 1; o < D; o <<= 1)
#pragma unroll
            for (int u = 0; u < 4; ++u) p[u] += __shfl_xor(p[u], o, 64);
#pragma unroll
        for (int u = 0; u < 4; ++u) {
            float e = __expf(p[u] * scale);
            acc += e * b2f((unsigned short)(w[u] >> 16));
            dsum += e;
        }
    }
    for (; j < j1; ++j) {
        unsigned int w = kvu[(size_t)csr_src[j] * 64 + lane];
        float p = qv * b2f((unsigned short)w);
#pragma unroll
        for (int o = 1; o < D; o <<= 1) p += __shfl_xor(p, o, 64);
        float e = __expf(p * scale);
        acc += e * b2f((unsigned short)(w >> 16));
        dsum += e;
    }
    float a = (dsum != 0.f) ? acc / dsum : 0.f;
    float sk = b2f(__builtin_nontemporal_load(
        (const unsigned short*)sb + (size_t)n * 64 + lane));
    float val = a + sk;
    if (RELU) val = fmaxf(val, 0.f);
    if constexpr (__hip_internal::is_same<OT, bf16>::value)
        out[(size_t)n * 64 + lane] = __float2bfloat16(val);  // hb: re-read by gemm2
    else
        __builtin_nontemporal_store(val, out + (size_t)n * 64 + lane);  // d_out: nt
}

extern "C" void kernel_launch(void* const* d_in, const int* in_sizes, int n_in,
                              void* d_out, int out_size, void* d_ws, size_t ws_size,
                              hipStream_t stream) {
    const float* x  = (const float*)d_in[0];
    const int*   ei = (const int*)d_in[1];
    const float* bq1 = (const float*)d_in[3];
    const float* bk1 = (const float*)d_in[5];
    const float* bv1 = (const float*)d_in[7];
    const float* bs1 = (const float*)d_in[9];
    const float* bq2 = (const float*)d_in[11];
    const float* bk2 = (const float*)d_in[13];
    const float* bv2 = (const float*)d_in[15];
    const float* bs2 = (const float*)d_in[17];

    WPtrs wp;
    wp.p[0] = (const float*)d_in[2];
    wp.p[1] = (const float*)d_in[4];
    wp.p[2] = (const float*)d_in[6];
    wp.p[3] = (const float*)d_in[8];
    wp.p[4] = (const float*)d_in[10];
    wp.p[5] = (const float*)d_in[12];
    wp.p[6] = (const float*)d_in[14];
    wp.p[7] = (const float*)d_in[16];

    const size_t N = N_NODES;
    bf16* xb  = (bf16*)d_ws;                 // NPAD*128
    bf16* hb  = xb + (size_t)NPAD * 128;     // NPAD*64
    bf16* qb  = hb + (size_t)NPAD * 64;      // N*64
    bf16* kvb = qb + N * 64;                 // 2*N*64 interleaved
    bf16* wb  = kvb + 2 * N * 64;            // 49152
    bf16* sb  = wb + 49152;                  // N*64 (bf16)
    int* deg  = (int*)(sb + N * 64);         // N
    int* off  = deg + N_NODES;               // N+1
    int* gcur = off + N_NODES + 1;           // NBK*CURSTRIDE
    int* bsum = gcur + N_NODES;              // NB_SCAN
    int* boff = bsum + NB_SCAN;              // NB_SCAN+1
    int* csr  = boff + NB_SCAN + 1;          // E
    unsigned int* pairs = (unsigned int*)(csr + N_EDGES); // E

    const int aggGrid = (N_NODES * 64 + 255) / 256;

    // ---------------- prep + CSR ----------------
    hipMemsetAsync(deg, 0, N_NODES * sizeof(int), stream);
    prep<<<dim3(1024, 3), 256, 0, stream>>>(x, xb, wp, wb, ei, deg);
    scan1<<<NB_SCAN, 256, 0, stream>>>(deg, off, bsum);
    scan2<<<1, 256, 0, stream>>>(bsum, boff);
    scan3<<<NB_SCAN, 256, 0, stream>>>(off, boff, gcur);

    // ---------------- Layer 1 (gemm + pass-A binning fused) ----------------
    gemm1_scatter<<<GEMM_BLKS + SCAT_BLKS, 256, 0, stream>>>(
        xb, wb, bq1, bk1, bv1, bs1, qb, kvb, sb, ei, off, gcur, pairs);
    passB<<<NBK, 256, 0, stream>>>(off, pairs, csr);
    agg_csr<4, true, bf16><<<aggGrid, 256, 0, stream>>>(off, csr, qb,
                                                        (const unsigned int*)kvb, sb, hb);

    // ---------------- Layer 2 ----------------
    gemm2<<<GEMM_BLKS, 256, 0, stream>>>(hb, wb + 32768, bq2, bk2, bv2, bs2,
                                         qb, kvb, sb);
    agg_csr<1, false, float><<<aggGrid, 256, 0, stream>>>(off, csr, qb,
                                                          (const unsigned int*)kvb, sb,
                                                          (float*)d_out);
}

// Round 7
// 316.183 us; speedup vs baseline: 1.0871x; 1.0459x over previous
//
#include <hip/hip_runtime.h>
#include <hip/hip_bf16.h>

// ROUND 23. r22 WIN (330.7, best). agg at structural gather ceiling
// (62.7us x2, 1.53 TB/s random-256B fill, ILP-insensitive per r15/r16).
// This round: the latency-bound gemms (MfmaUtil 1.2%, VALU 3%, HBM 12%,
// occ 21-27% -> grid-capped at 782 blocks = ~12 waves/CU).
//  1) 32-row tiles (MR=2): 1563 blocks -> ~24 waves/CU, acc VGPR halved.
//  2) prep x-conv vectorized 8-wide (was scalar 4B/2B per thread).
// Predict: gemm1_scatter occ 26->~50%, 55-60 -> ~40us; gemm2 -> ~18;
// prep -> ~12; total 330.7 -> ~285-295. agg unchanged.

#define N_NODES 50000
#define N_EDGES 800000
#define NB_SCAN 196   // ceil(50000/256)
#define NPAD    50048 // allocation pad (>= 1563*32 = 50016)
#define GEMM_BLKS 1563 // ceil(50000/32), 32-row tiles
#define EPB 2048       // edges per scatter block
#define SCAT_BLKS 391  // ceil(800000/2048)
#define NBK 196        // buckets of 256 nodes (dst>>8)
#define CURSTRIDE 16   // one cursor per 64B line

using bf16 = __hip_bfloat16;
typedef __attribute__((ext_vector_type(8))) short bf16x8;
typedef __attribute__((ext_vector_type(4))) float f32x4;

__device__ __forceinline__ float b2f(unsigned short u) {
    unsigned int x = ((unsigned int)u) << 16;
    return __builtin_bit_cast(float, x);
}
__device__ __forceinline__ short f2b(float f) {
    return (short)__builtin_bit_cast(unsigned short, __float2bfloat16(f));
}

struct WPtrs { const float* p[8]; };

// ---------------- fused prep: conv_x / conv_w / hist ----------------
__global__ __launch_bounds__(256) void prep(const float* __restrict__ x,
                                            bf16* __restrict__ xb,
                                            WPtrs wp, bf16* __restrict__ wb,
                                            const int* __restrict__ ei,
                                            int* __restrict__ deg) {
    const int gs = gridDim.x * 256;
    const int t0 = blockIdx.x * 256 + threadIdx.x;
    if (blockIdx.y == 0) {
        // vectorized: 8 elems/iter (2x float4 load, 1x 16B store)
        for (int i = t0; i < N_NODES * 16; i += gs) {
            const float* px = x + (size_t)i * 8;
            f32x4 v0 = *(const f32x4*)px;
            f32x4 v1 = *(const f32x4*)(px + 4);
            bf16x8 o;
#pragma unroll
            for (int q = 0; q < 4; ++q) {
                o[q]     = f2b(v0[q]);
                o[q + 4] = f2b(v1[q]);
            }
            *(bf16x8*)(xb + (size_t)i * 8) = o;
        }
    } else if (blockIdx.y == 1) {
        for (int i = t0; i < 49152; i += gs) {
            int y, o;
            if (i < 32768) { y = i >> 13; o = i & 8191; }
            else { y = 4 + ((i - 32768) >> 12); o = (i - 32768) & 4095; }
            wb[i] = __float2bfloat16(wp.p[y][o]);
        }
    } else {
        for (int e = t0; e < N_EDGES; e += gs)
            atomicAdd(&deg[ei[N_EDGES + e]], 1);
    }
}

// ------------- MFMA GEMM body (MR*16-row tile, 4 weight mats) -------------
template <int K, int MR>
__device__ __forceinline__ void gemm_body(
    int blk, int tid,
    const bf16* __restrict__ A, const bf16* __restrict__ wb,
    const float* __restrict__ bq, const float* __restrict__ bk,
    const float* __restrict__ bv, const float* __restrict__ bs,
    bf16* __restrict__ qb, bf16* __restrict__ kvb, bf16* __restrict__ sb) {
    const int wave = tid >> 6;
    const int lane = tid & 63;
    const int row0 = blk * (MR * 16);
    const int m  = lane & 15;
    const int kg = lane >> 4;
    const bf16* W = wb + (size_t)wave * 64 * K;

    f32x4 acc[MR][4];
#pragma unroll
    for (int i = 0; i < MR; ++i)
#pragma unroll
        for (int j = 0; j < 4; ++j) acc[i][j] = (f32x4){0.f, 0.f, 0.f, 0.f};

#pragma unroll
    for (int k0 = 0; k0 < K; k0 += 32) {
        bf16x8 a[MR], b[4];
#pragma unroll
        for (int i = 0; i < MR; ++i)
            a[i] = *(const bf16x8*)(A + (size_t)(row0 + i * 16 + m) * K + k0 + kg * 8);
#pragma unroll
        for (int j = 0; j < 4; ++j)
            b[j] = *(const bf16x8*)(W + (size_t)(j * 16 + m) * K + k0 + kg * 8);
#pragma unroll
        for (int i = 0; i < MR; ++i)
#pragma unroll
            for (int j = 0; j < 4; ++j)
                acc[i][j] = __builtin_amdgcn_mfma_f32_16x16x32_bf16(a[i], b[j], acc[i][j], 0, 0, 0);
    }

    const int crow = (lane >> 4) * 4;
    const int ccol = lane & 15;
    const float* B = (wave == 0) ? bq : (wave == 1) ? bk : (wave == 2) ? bv : bs;
    float bias[4];
#pragma unroll
    for (int j = 0; j < 4; ++j) bias[j] = B[j * 16 + ccol];

#pragma unroll
    for (int i = 0; i < MR; ++i)
#pragma unroll
        for (int r = 0; r < 4; ++r) {
            int gr = row0 + i * 16 + crow + r;
            if (gr >= N_NODES) continue;
#pragma unroll
            for (int j = 0; j < 4; ++j) {
                float val = acc[i][j][r] + bias[j];
                size_t idx = (size_t)gr * 64 + j * 16 + ccol;
                if (wave == 0) qb[idx] = __float2bfloat16(val);
                else if (wave == 1) kvb[idx * 2] = __float2bfloat16(val);
                else if (wave == 2) kvb[idx * 2 + 1] = __float2bfloat16(val);
                else sb[idx] = __float2bfloat16(val);
            }
        }
}

// layer-1 GEMM + pass-A LDS-binned scatter fused.
__global__ __launch_bounds__(256) void gemm1_scatter(
    const bf16* __restrict__ A, const bf16* __restrict__ wb,
    const float* __restrict__ bq, const float* __restrict__ bk,
    const float* __restrict__ bv, const float* __restrict__ bs,
    bf16* __restrict__ qb, bf16* __restrict__ kvb, bf16* __restrict__ sb,
    const int* __restrict__ ei, const int* __restrict__ off,
    int* __restrict__ gcur, unsigned int* __restrict__ pairs) {
    __shared__ int hist[256];
    __shared__ int sm[256];
    __shared__ int obs[NBK];
    __shared__ unsigned int stage[EPB];

    if (blockIdx.x < GEMM_BLKS) {
        gemm_body<128, 2>(blockIdx.x, threadIdx.x, A, wb, bq, bk, bv, bs, qb, kvb, sb);
        return;
    }
    const int t = threadIdx.x;
    const int e0 = (blockIdx.x - GEMM_BLKS) * EPB;
    hist[t] = 0;
    __syncthreads();

    // per-edge: bucket + within-bucket rank via LDS atomics
    unsigned int pk[8];
    int bb[8], rr[8];
#pragma unroll
    for (int u = 0; u < 8; ++u) {
        const int e = e0 + u * 256 + t;
        if (e < N_EDGES) {
            int d  = ei[N_EDGES + e];
            int sv = ei[e];
            pk[u] = ((unsigned int)d << 16) | (unsigned int)sv;
            bb[u] = d >> 8;
            rr[u] = atomicAdd(&hist[bb[u]], 1);
        } else {
            bb[u] = -1;
        }
    }
    __syncthreads();

    // block-wide inclusive scan of hist (256 entries, Hillis-Steele)
    int hv = hist[t];
    sm[t] = hv;
    __syncthreads();
    for (int st = 1; st < 256; st <<= 1) {
        int tmp = (t >= st) ? sm[t - st] : 0;
        __syncthreads();
        sm[t] += tmp;
        __syncthreads();
    }
    const int total = sm[255];

    // one global reservation per non-empty bucket
    if (t < NBK && hv > 0) {
        int g = atomicAdd(&gcur[t * CURSTRIDE], hv);
        obs[t] = off[t << 8] + g - (sm[t] - hv);  // global base minus local run start
    }
    __syncthreads();

    // bin into LDS staging (bucket-sorted)
#pragma unroll
    for (int u = 0; u < 8; ++u)
        if (bb[u] >= 0) stage[(sm[bb[u]] - hist[bb[u]]) + rr[u]] = pk[u];
    __syncthreads();

    // copy-out: consecutive j within a bucket run -> contiguous global stores
    for (int j = t; j < total; j += 256) {
        unsigned int pr = stage[j];
        int b = pr >> 24;  // dst>>8
        pairs[obs[b] + j] = pr;
    }
}

// Pass B: one block per bucket (256 nodes). off-window in LDS, LDS-rank,
// dense stores into the bucket's contiguous csr region.
__global__ __launch_bounds__(256) void passB(const int* __restrict__ off,
                                             const unsigned int* __restrict__ pairs,
                                             int* __restrict__ csr) {
    __shared__ int lcnt[256];
    __shared__ int loff[256];
    const int b = blockIdx.x;
    const int n0 = b << 8;
    const int nend = (n0 + 256 < N_NODES) ? n0 + 256 : N_NODES;
    lcnt[threadIdx.x] = 0;
    if (n0 + threadIdx.x < nend) loff[threadIdx.x] = off[n0 + threadIdx.x];
    const int p0 = off[n0];
    const int p1 = off[nend];
    __syncthreads();
    for (int j = p0 + threadIdx.x; j < p1; j += 256) {
        unsigned int pr = pairs[j];
        int d  = (int)(pr >> 16);
        int sv = (int)(pr & 0xffffu);
        int r = atomicAdd(&lcnt[d - n0], 1);
        csr[loff[d - n0] + r] = sv;
    }
}

__global__ __launch_bounds__(256) void gemm2(
    const bf16* __restrict__ A, const bf16* __restrict__ wb,
    const float* __restrict__ bq, const float* __restrict__ bk,
    const float* __restrict__ bv, const float* __restrict__ bs,
    bf16* __restrict__ qb, bf16* __restrict__ kvb, bf16* __restrict__ sb) {
    gemm_body<64, 2>(blockIdx.x, threadIdx.x, A, wb, bq, bk, bv, bs, qb, kvb, sb);
}

// ---------------- CSR scan ----------------
__global__ __launch_bounds__(256) void scan1(const int* __restrict__ deg,
                                             int* __restrict__ off,
                                             int* __restrict__ bsum) {
    __shared__ int sm[256];
    int i = blockIdx.x * 256 + threadIdx.x;
    int v = (i < N_NODES) ? deg[i] : 0;
    sm[threadIdx.x] = v;
    __syncthreads();
    for (int st = 1; st < 256; st <<= 1) {
        int t = (threadIdx.x >= (unsigned)st) ? sm[threadIdx.x - st] : 0;
        __syncthreads();
        sm[threadIdx.x] += t;
        __syncthreads();
    }
    if (i < N_NODES) off[i] = sm[threadIdx.x] - v;
    if (threadIdx.x == 255) bsum[blockIdx.x] = sm[255];
}

__global__ __launch_bounds__(256) void scan2(const int* __restrict__ bsum,
                                             int* __restrict__ boff) {
    __shared__ int sm[256];
    int b = threadIdx.x;
    int v = (b < NB_SCAN) ? bsum[b] : 0;
    sm[b] = v;
    __syncthreads();
    for (int st = 1; st < 256; st <<= 1) {
        int t = (b >= st) ? sm[b - st] : 0;
        __syncthreads();
        sm[b] += t;
        __syncthreads();
    }
    if (b < NB_SCAN) boff[b] = sm[b] - v;
    if (b == 255) boff[NB_SCAN] = sm[255];
}

__global__ __launch_bounds__(256) void scan3(int* __restrict__ off,
                                             const int* __restrict__ boff,
                                             int* __restrict__ gcur) {
    int i = blockIdx.x * 256 + threadIdx.x;
    if (i < N_NODES) off[i] = off[i] + boff[blockIdx.x];
    if (i == 0) off[N_NODES] = boff[NB_SCAN];
    if (i < NBK * CURSTRIDE) gcur[i] = 0;
}

// ------------- Aggregation: wave/node, nt streaming, unroll 16 -------------
template <int H, bool RELU, typename OT>  // D = 64/H
__global__ __launch_bounds__(256) void agg_csr(const int* __restrict__ off,
                                               const int* __restrict__ csr_src,
                                               const bf16* __restrict__ qb,
                                               const unsigned int* __restrict__ kvu,
                                               const bf16* __restrict__ sb,
                                               OT* __restrict__ out) {
    const int D = 64 / H;
    const float scale = (D == 16) ? 0.25f : 0.125f;
    const int lane = threadIdx.x & 63;
    const int n = (blockIdx.x * 256 + threadIdx.x) >> 6;
    if (n >= N_NODES) return;

    const float qv = b2f(__builtin_nontemporal_load(
        (const unsigned short*)qb + (size_t)n * 64 + lane));
    float acc = 0.f, dsum = 0.f;
    int j = off[n];
    const int j1 = off[n + 1];

    for (; j + 15 < j1; j += 16) {
        unsigned int w[16];
#pragma unroll
        for (int u = 0; u < 16; ++u)
            w[u] = kvu[(size_t)csr_src[j + u] * 64 + lane];
        float p[16];
#pragma unroll
        for (int u = 0; u < 16; ++u) p[u] = qv * b2f((unsigned short)w[u]);
#pragma unroll
        for (int o = 1; o < D; o <<= 1)
#pragma unroll
            for (int u = 0; u < 16; ++u) p[u] += __shfl_xor(p[u], o, 64);
#pragma unroll
        for (int u = 0; u < 16; ++u) {
            float e = __expf(p[u] * scale);
            acc += e * b2f((unsigned short)(w[u] >> 16));
            dsum += e;
        }
    }
    for (; j + 3 < j1; j += 4) {
        unsigned int w[4];
#pragma unroll
        for (int u = 0; u < 4; ++u)
            w[u] = kvu[(size_t)csr_src[j + u] * 64 + lane];
        float p[4];
#pragma unroll
        for (int u = 0; u < 4; ++u) p[u] = qv * b2f((unsigned short)w[u]);
#pragma unroll
        for (int o = 1; o < D; o <<= 1)
#pragma unroll
            for (int u = 0; u < 4; ++u) p[u] += __shfl_xor(p[u], o, 64);
#pragma unroll
        for (int u = 0; u < 4; ++u) {
            float e = __expf(p[u] * scale);
            acc += e * b2f((unsigned short)(w[u] >> 16));
            dsum += e;
        }
    }
    for (; j < j1; ++j) {
        unsigned int w = kvu[(size_t)csr_src[j] * 64 + lane];
        float p = qv * b2f((unsigned short)w);
#pragma unroll
        for (int o = 1; o < D; o <<= 1) p += __shfl_xor(p, o, 64);
        float e = __expf(p * scale);
        acc += e * b2f((unsigned short)(w >> 16));
        dsum += e;
    }
    float a = (dsum != 0.f) ? acc / dsum : 0.f;
    float sk = b2f(__builtin_nontemporal_load(
        (const unsigned short*)sb + (size_t)n * 64 + lane));
    float val = a + sk;
    if (RELU) val = fmaxf(val, 0.f);
    if constexpr (__hip_internal::is_same<OT, bf16>::value)
        out[(size_t)n * 64 + lane] = __float2bfloat16(val);  // hb: re-read by gemm2
    else
        __builtin_nontemporal_store(val, out + (size_t)n * 64 + lane);  // d_out: nt
}

extern "C" void kernel_launch(void* const* d_in, const int* in_sizes, int n_in,
                              void* d_out, int out_size, void* d_ws, size_t ws_size,
                              hipStream_t stream) {
    const float* x  = (const float*)d_in[0];
    const int*   ei = (const int*)d_in[1];
    const float* bq1 = (const float*)d_in[3];
    const float* bk1 = (const float*)d_in[5];
    const float* bv1 = (const float*)d_in[7];
    const float* bs1 = (const float*)d_in[9];
    const float* bq2 = (const float*)d_in[11];
    const float* bk2 = (const float*)d_in[13];
    const float* bv2 = (const float*)d_in[15];
    const float* bs2 = (const float*)d_in[17];

    WPtrs wp;
    wp.p[0] = (const float*)d_in[2];
    wp.p[1] = (const float*)d_in[4];
    wp.p[2] = (const float*)d_in[6];
    wp.p[3] = (const float*)d_in[8];
    wp.p[4] = (const float*)d_in[10];
    wp.p[5] = (const float*)d_in[12];
    wp.p[6] = (const float*)d_in[14];
    wp.p[7] = (const float*)d_in[16];

    const size_t N = N_NODES;
    bf16* xb  = (bf16*)d_ws;                 // NPAD*128
    bf16* hb  = xb + (size_t)NPAD * 128;     // NPAD*64
    bf16* qb  = hb + (size_t)NPAD * 64;      // N*64
    bf16* kvb = qb + N * 64;                 // 2*N*64 interleaved
    bf16* wb  = kvb + 2 * N * 64;            // 49152
    bf16* sb  = wb + 49152;                  // N*64 (bf16)
    int* deg  = (int*)(sb + N * 64);         // N
    int* off  = deg + N_NODES;               // N+1
    int* gcur = off + N_NODES + 1;           // NBK*CURSTRIDE
    int* bsum = gcur + N_NODES;              // NB_SCAN
    int* boff = bsum + NB_SCAN;              // NB_SCAN+1
    int* csr  = boff + NB_SCAN + 1;          // E
    unsigned int* pairs = (unsigned int*)(csr + N_EDGES); // E

    const int aggGrid = (N_NODES * 64 + 255) / 256;

    // ---------------- prep + CSR ----------------
    hipMemsetAsync(deg, 0, N_NODES * sizeof(int), stream);
    prep<<<dim3(1024, 3), 256, 0, stream>>>(x, xb, wp, wb, ei, deg);
    scan1<<<NB_SCAN, 256, 0, stream>>>(deg, off, bsum);
    scan2<<<1, 256, 0, stream>>>(bsum, boff);
    scan3<<<NB_SCAN, 256, 0, stream>>>(off, boff, gcur);

    // ---------------- Layer 1 (gemm + pass-A binning fused) ----------------
    gemm1_scatter<<<GEMM_BLKS + SCAT_BLKS, 256, 0, stream>>>(
        xb, wb, bq1, bk1, bv1, bs1, qb, kvb, sb, ei, off, gcur, pairs);
    passB<<<NBK, 256, 0, stream>>>(off, pairs, csr);
    agg_csr<4, true, bf16><<<aggGrid, 256, 0, stream>>>(off, csr, qb,
                                                        (const unsigned int*)kvb, sb, hb);

    // ---------------- Layer 2 ----------------
    gemm2<<<GEMM_BLKS, 256, 0, stream>>>(hb, wb + 32768, bq2, bk2, bv2, bs2,
                                         qb, kvb, sb);
    agg_csr<1, false, float><<<aggGrid, 256, 0, stream>>>(off, csr, qb,
                                                          (const unsigned int*)kvb, sb,
                                                          (float*)d_out);
}

// Round 8
// 301.028 us; speedup vs baseline: 1.1419x; 1.0503x over previous
//
#include <hip/hip_runtime.h>
#include <hip/hip_bf16.h>

// ROUND 24. r23 WIN (316.2, best): 32-row tiles fixed gemm occupancy (both
// gemms off top-5). Now agg_csr x2 = 130us/316 (41%). Fill-bound model
// DISPROVEN: misses fell 26% (r19->r23) but agg time fell 1.4%. Signature
// (VALU 53%, occ 57%, HBM 19%, ILP-insensitive) = per-edge dependent chain:
// 4-6x (ds_swizzle ~25cyc + add) + exp per edge. Changes (agg only):
//  1) DPP rotate-reduce (v_add_f32_dpp row_ror 8/4/2/1) replaces shfl_xor
//     within 16-lane rows: VALU-only, ~2-4cyc/step vs ~25, frees DS pipe.
//     H=1 keeps 2 residual shfl_xor (16,32) cross-row.
//  2) exp2f with folded scale (saves 1 mul/edge).
//  3) 32-bit gather index ((csr<<6)|lane) -> cheap addressing.
// Predict: agg 64.8 -> 50-57us each, total -> ~295-305. If agg unchanged:
// chain theory disproven -> fill model back; next = fp8-k or structural stop.

#define N_NODES 50000
#define N_EDGES 800000
#define NB_SCAN 196   // ceil(50000/256)
#define NPAD    50048 // allocation pad (>= 1563*32 = 50016)
#define GEMM_BLKS 1563 // ceil(50000/32), 32-row tiles
#define EPB 2048       // edges per scatter block
#define SCAT_BLKS 391  // ceil(800000/2048)
#define NBK 196        // buckets of 256 nodes (dst>>8)
#define CURSTRIDE 16   // one cursor per 64B line

using bf16 = __hip_bfloat16;
typedef __attribute__((ext_vector_type(8))) short bf16x8;
typedef __attribute__((ext_vector_type(4))) float f32x4;

__device__ __forceinline__ float b2f(unsigned short u) {
    unsigned int x = ((unsigned int)u) << 16;
    return __builtin_bit_cast(float, x);
}
__device__ __forceinline__ short f2b(float f) {
    return (short)__builtin_bit_cast(unsigned short, __float2bfloat16(f));
}

// DPP rotate-add within 16-lane row: p += rotate(p, N). Butterfly over
// rotations 8,4,2,1 sums all 16 lanes into every lane (commutative add).
template <int N>
__device__ __forceinline__ float rradd(float p) {
    int vi = __builtin_bit_cast(int, p);
    int mv = __builtin_amdgcn_update_dpp(vi, vi, 0x120 | N, 0xF, 0xF, false);
    return p + __builtin_bit_cast(float, mv);
}
template <int D>
__device__ __forceinline__ float head_reduce(float p) {
    p = rradd<8>(p); p = rradd<4>(p); p = rradd<2>(p); p = rradd<1>(p);
    if constexpr (D == 64) {
        p += __shfl_xor(p, 16, 64);
        p += __shfl_xor(p, 32, 64);
    }
    return p;
}

struct WPtrs { const float* p[8]; };

// ---------------- fused prep: conv_x / conv_w / hist ----------------
__global__ __launch_bounds__(256) void prep(const float* __restrict__ x,
                                            bf16* __restrict__ xb,
                                            WPtrs wp, bf16* __restrict__ wb,
                                            const int* __restrict__ ei,
                                            int* __restrict__ deg) {
    const int gs = gridDim.x * 256;
    const int t0 = blockIdx.x * 256 + threadIdx.x;
    if (blockIdx.y == 0) {
        // vectorized: 8 elems/iter (2x float4 load, 1x 16B store)
        for (int i = t0; i < N_NODES * 16; i += gs) {
            const float* px = x + (size_t)i * 8;
            f32x4 v0 = *(const f32x4*)px;
            f32x4 v1 = *(const f32x4*)(px + 4);
            bf16x8 o;
#pragma unroll
            for (int q = 0; q < 4; ++q) {
                o[q]     = f2b(v0[q]);
                o[q + 4] = f2b(v1[q]);
            }
            *(bf16x8*)(xb + (size_t)i * 8) = o;
        }
    } else if (blockIdx.y == 1) {
        for (int i = t0; i < 49152; i += gs) {
            int y, o;
            if (i < 32768) { y = i >> 13; o = i & 8191; }
            else { y = 4 + ((i - 32768) >> 12); o = (i - 32768) & 4095; }
            wb[i] = __float2bfloat16(wp.p[y][o]);
        }
    } else {
        for (int e = t0; e < N_EDGES; e += gs)
            atomicAdd(&deg[ei[N_EDGES + e]], 1);
    }
}

// ------------- MFMA GEMM body (MR*16-row tile, 4 weight mats) -------------
template <int K, int MR>
__device__ __forceinline__ void gemm_body(
    int blk, int tid,
    const bf16* __restrict__ A, const bf16* __restrict__ wb,
    const float* __restrict__ bq, const float* __restrict__ bk,
    const float* __restrict__ bv, const float* __restrict__ bs,
    bf16* __restrict__ qb, bf16* __restrict__ kvb, bf16* __restrict__ sb) {
    const int wave = tid >> 6;
    const int lane = tid & 63;
    const int row0 = blk * (MR * 16);
    const int m  = lane & 15;
    const int kg = lane >> 4;
    const bf16* W = wb + (size_t)wave * 64 * K;

    f32x4 acc[MR][4];
#pragma unroll
    for (int i = 0; i < MR; ++i)
#pragma unroll
        for (int j = 0; j < 4; ++j) acc[i][j] = (f32x4){0.f, 0.f, 0.f, 0.f};

#pragma unroll
    for (int k0 = 0; k0 < K; k0 += 32) {
        bf16x8 a[MR], b[4];
#pragma unroll
        for (int i = 0; i < MR; ++i)
            a[i] = *(const bf16x8*)(A + (size_t)(row0 + i * 16 + m) * K + k0 + kg * 8);
#pragma unroll
        for (int j = 0; j < 4; ++j)
            b[j] = *(const bf16x8*)(W + (size_t)(j * 16 + m) * K + k0 + kg * 8);
#pragma unroll
        for (int i = 0; i < MR; ++i)
#pragma unroll
            for (int j = 0; j < 4; ++j)
                acc[i][j] = __builtin_amdgcn_mfma_f32_16x16x32_bf16(a[i], b[j], acc[i][j], 0, 0, 0);
    }

    const int crow = (lane >> 4) * 4;
    const int ccol = lane & 15;
    const float* B = (wave == 0) ? bq : (wave == 1) ? bk : (wave == 2) ? bv : bs;
    float bias[4];
#pragma unroll
    for (int j = 0; j < 4; ++j) bias[j] = B[j * 16 + ccol];

#pragma unroll
    for (int i = 0; i < MR; ++i)
#pragma unroll
        for (int r = 0; r < 4; ++r) {
            int gr = row0 + i * 16 + crow + r;
            if (gr >= N_NODES) continue;
#pragma unroll
            for (int j = 0; j < 4; ++j) {
                float val = acc[i][j][r] + bias[j];
                size_t idx = (size_t)gr * 64 + j * 16 + ccol;
                if (wave == 0) qb[idx] = __float2bfloat16(val);
                else if (wave == 1) kvb[idx * 2] = __float2bfloat16(val);
                else if (wave == 2) kvb[idx * 2 + 1] = __float2bfloat16(val);
                else sb[idx] = __float2bfloat16(val);
            }
        }
}

// layer-1 GEMM + pass-A LDS-binned scatter fused.
__global__ __launch_bounds__(256) void gemm1_scatter(
    const bf16* __restrict__ A, const bf16* __restrict__ wb,
    const float* __restrict__ bq, const float* __restrict__ bk,
    const float* __restrict__ bv, const float* __restrict__ bs,
    bf16* __restrict__ qb, bf16* __restrict__ kvb, bf16* __restrict__ sb,
    const int* __restrict__ ei, const int* __restrict__ off,
    int* __restrict__ gcur, unsigned int* __restrict__ pairs) {
    __shared__ int hist[256];
    __shared__ int sm[256];
    __shared__ int obs[NBK];
    __shared__ unsigned int stage[EPB];

    if (blockIdx.x < GEMM_BLKS) {
        gemm_body<128, 2>(blockIdx.x, threadIdx.x, A, wb, bq, bk, bv, bs, qb, kvb, sb);
        return;
    }
    const int t = threadIdx.x;
    const int e0 = (blockIdx.x - GEMM_BLKS) * EPB;
    hist[t] = 0;
    __syncthreads();

    // per-edge: bucket + within-bucket rank via LDS atomics
    unsigned int pk[8];
    int bb[8], rr[8];
#pragma unroll
    for (int u = 0; u < 8; ++u) {
        const int e = e0 + u * 256 + t;
        if (e < N_EDGES) {
            int d  = ei[N_EDGES + e];
            int sv = ei[e];
            pk[u] = ((unsigned int)d << 16) | (unsigned int)sv;
            bb[u] = d >> 8;
            rr[u] = atomicAdd(&hist[bb[u]], 1);
        } else {
            bb[u] = -1;
        }
    }
    __syncthreads();

    // block-wide inclusive scan of hist (256 entries, Hillis-Steele)
    int hv = hist[t];
    sm[t] = hv;
    __syncthreads();
    for (int st = 1; st < 256; st <<= 1) {
        int tmp = (t >= st) ? sm[t - st] : 0;
        __syncthreads();
        sm[t] += tmp;
        __syncthreads();
    }
    const int total = sm[255];

    // one global reservation per non-empty bucket
    if (t < NBK && hv > 0) {
        int g = atomicAdd(&gcur[t * CURSTRIDE], hv);
        obs[t] = off[t << 8] + g - (sm[t] - hv);  // global base minus local run start
    }
    __syncthreads();

    // bin into LDS staging (bucket-sorted)
#pragma unroll
    for (int u = 0; u < 8; ++u)
        if (bb[u] >= 0) stage[(sm[bb[u]] - hist[bb[u]]) + rr[u]] = pk[u];
    __syncthreads();

    // copy-out: consecutive j within a bucket run -> contiguous global stores
    for (int j = t; j < total; j += 256) {
        unsigned int pr = stage[j];
        int b = pr >> 24;  // dst>>8
        pairs[obs[b] + j] = pr;
    }
}

// Pass B: one block per bucket (256 nodes). off-window in LDS, LDS-rank,
// dense stores into the bucket's contiguous csr region.
__global__ __launch_bounds__(256) void passB(const int* __restrict__ off,
                                             const unsigned int* __restrict__ pairs,
                                             int* __restrict__ csr) {
    __shared__ int lcnt[256];
    __shared__ int loff[256];
    const int b = blockIdx.x;
    const int n0 = b << 8;
    const int nend = (n0 + 256 < N_NODES) ? n0 + 256 : N_NODES;
    lcnt[threadIdx.x] = 0;
    if (n0 + threadIdx.x < nend) loff[threadIdx.x] = off[n0 + threadIdx.x];
    const int p0 = off[n0];
    const int p1 = off[nend];
    __syncthreads();
    for (int j = p0 + threadIdx.x; j < p1; j += 256) {
        unsigned int pr = pairs[j];
        int d  = (int)(pr >> 16);
        int sv = (int)(pr & 0xffffu);
        int r = atomicAdd(&lcnt[d - n0], 1);
        csr[loff[d - n0] + r] = sv;
    }
}

__global__ __launch_bounds__(256) void gemm2(
    const bf16* __restrict__ A, const bf16* __restrict__ wb,
    const float* __restrict__ bq, const float* __restrict__ bk,
    const float* __restrict__ bv, const float* __restrict__ bs,
    bf16* __restrict__ qb, bf16* __restrict__ kvb, bf16* __restrict__ sb) {
    gemm_body<64, 2>(blockIdx.x, threadIdx.x, A, wb, bq, bk, bv, bs, qb, kvb, sb);
}

// ---------------- CSR scan ----------------
__global__ __launch_bounds__(256) void scan1(const int* __restrict__ deg,
                                             int* __restrict__ off,
                                             int* __restrict__ bsum) {
    __shared__ int sm[256];
    int i = blockIdx.x * 256 + threadIdx.x;
    int v = (i < N_NODES) ? deg[i] : 0;
    sm[threadIdx.x] = v;
    __syncthreads();
    for (int st = 1; st < 256; st <<= 1) {
        int t = (threadIdx.x >= (unsigned)st) ? sm[threadIdx.x - st] : 0;
        __syncthreads();
        sm[threadIdx.x] += t;
        __syncthreads();
    }
    if (i < N_NODES) off[i] = sm[threadIdx.x] - v;
    if (threadIdx.x == 255) bsum[blockIdx.x] = sm[255];
}

__global__ __launch_bounds__(256) void scan2(const int* __restrict__ bsum,
                                             int* __restrict__ boff) {
    __shared__ int sm[256];
    int b = threadIdx.x;
    int v = (b < NB_SCAN) ? bsum[b] : 0;
    sm[b] = v;
    __syncthreads();
    for (int st = 1; st < 256; st <<= 1) {
        int t = (b >= st) ? sm[b - st] : 0;
        __syncthreads();
        sm[b] += t;
        __syncthreads();
    }
    if (b < NB_SCAN) boff[b] = sm[b] - v;
    if (b == 255) boff[NB_SCAN] = sm[255];
}

__global__ __launch_bounds__(256) void scan3(int* __restrict__ off,
                                             const int* __restrict__ boff,
                                             int* __restrict__ gcur) {
    int i = blockIdx.x * 256 + threadIdx.x;
    if (i < N_NODES) off[i] = off[i] + boff[blockIdx.x];
    if (i == 0) off[N_NODES] = boff[NB_SCAN];
    if (i < NBK * CURSTRIDE) gcur[i] = 0;
}

// --------- Aggregation: wave/node, DPP rotate-reduce, unroll 16 ---------
template <int H, bool RELU, typename OT>  // D = 64/H
__global__ __launch_bounds__(256) void agg_csr(const int* __restrict__ off,
                                               const int* __restrict__ csr_src,
                                               const bf16* __restrict__ qb,
                                               const unsigned int* __restrict__ kvu,
                                               const bf16* __restrict__ sb,
                                               OT* __restrict__ out) {
    const int D = 64 / H;
    // exp(p*scale) = exp2(p * scale * log2e), scale = 1/sqrt(D)
    const float SC = ((D == 16) ? 0.25f : 0.125f) * 1.4426950408889634f;
    const int lane = threadIdx.x & 63;
    const int n = (blockIdx.x * 256 + threadIdx.x) >> 6;
    if (n >= N_NODES) return;

    const float qv = b2f(__builtin_nontemporal_load(
        (const unsigned short*)qb + (size_t)n * 64 + lane));
    float acc = 0.f, dsum = 0.f;
    int j = off[n];
    const int j1 = off[n + 1];

    for (; j + 15 < j1; j += 16) {
        unsigned int w[16];
#pragma unroll
        for (int u = 0; u < 16; ++u)
            w[u] = kvu[(((unsigned)csr_src[j + u]) << 6) | (unsigned)lane];
        float p[16];
#pragma unroll
        for (int u = 0; u < 16; ++u) p[u] = qv * b2f((unsigned short)w[u]);
#pragma unroll
        for (int u = 0; u < 16; ++u) p[u] = head_reduce<D>(p[u]);
#pragma unroll
        for (int u = 0; u < 16; ++u) {
            float e = exp2f(p[u] * SC);
            acc += e * b2f((unsigned short)(w[u] >> 16));
            dsum += e;
        }
    }
    for (; j + 3 < j1; j += 4) {
        unsigned int w[4];
#pragma unroll
        for (int u = 0; u < 4; ++u)
            w[u] = kvu[(((unsigned)csr_src[j + u]) << 6) | (unsigned)lane];
        float p[4];
#pragma unroll
        for (int u = 0; u < 4; ++u) p[u] = qv * b2f((unsigned short)w[u]);
#pragma unroll
        for (int u = 0; u < 4; ++u) p[u] = head_reduce<D>(p[u]);
#pragma unroll
        for (int u = 0; u < 4; ++u) {
            float e = exp2f(p[u] * SC);
            acc += e * b2f((unsigned short)(w[u] >> 16));
            dsum += e;
        }
    }
    for (; j < j1; ++j) {
        unsigned int w = kvu[(((unsigned)csr_src[j]) << 6) | (unsigned)lane];
        float p = head_reduce<D>(qv * b2f((unsigned short)w));
        float e = exp2f(p * SC);
        acc += e * b2f((unsigned short)(w >> 16));
        dsum += e;
    }
    float a = (dsum != 0.f) ? acc / dsum : 0.f;
    float sk = b2f(__builtin_nontemporal_load(
        (const unsigned short*)sb + (size_t)n * 64 + lane));
    float val = a + sk;
    if (RELU) val = fmaxf(val, 0.f);
    if constexpr (__hip_internal::is_same<OT, bf16>::value)
        out[(size_t)n * 64 + lane] = __float2bfloat16(val);  // hb: re-read by gemm2
    else
        __builtin_nontemporal_store(val, out + (size_t)n * 64 + lane);  // d_out: nt
}

extern "C" void kernel_launch(void* const* d_in, const int* in_sizes, int n_in,
                              void* d_out, int out_size, void* d_ws, size_t ws_size,
                              hipStream_t stream) {
    const float* x  = (const float*)d_in[0];
    const int*   ei = (const int*)d_in[1];
    const float* bq1 = (const float*)d_in[3];
    const float* bk1 = (const float*)d_in[5];
    const float* bv1 = (const float*)d_in[7];
    const float* bs1 = (const float*)d_in[9];
    const float* bq2 = (const float*)d_in[11];
    const float* bk2 = (const float*)d_in[13];
    const float* bv2 = (const float*)d_in[15];
    const float* bs2 = (const float*)d_in[17];

    WPtrs wp;
    wp.p[0] = (const float*)d_in[2];
    wp.p[1] = (const float*)d_in[4];
    wp.p[2] = (const float*)d_in[6];
    wp.p[3] = (const float*)d_in[8];
    wp.p[4] = (const float*)d_in[10];
    wp.p[5] = (const float*)d_in[12];
    wp.p[6] = (const float*)d_in[14];
    wp.p[7] = (const float*)d_in[16];

    const size_t N = N_NODES;
    bf16* xb  = (bf16*)d_ws;                 // NPAD*128
    bf16* hb  = xb + (size_t)NPAD * 128;     // NPAD*64
    bf16* qb  = hb + (size_t)NPAD * 64;      // N*64
    bf16* kvb = qb + N * 64;                 // 2*N*64 interleaved
    bf16* wb  = kvb + 2 * N * 64;            // 49152
    bf16* sb  = wb + 49152;                  // N*64 (bf16)
    int* deg  = (int*)(sb + N * 64);         // N
    int* off  = deg + N_NODES;               // N+1
    int* gcur = off + N_NODES + 1;           // NBK*CURSTRIDE
    int* bsum = gcur + N_NODES;              // NB_SCAN
    int* boff = bsum + NB_SCAN;              // NB_SCAN+1
    int* csr  = boff + NB_SCAN + 1;          // E
    unsigned int* pairs = (unsigned int*)(csr + N_EDGES); // E

    const int aggGrid = (N_NODES * 64 + 255) / 256;

    // ---------------- prep + CSR ----------------
    hipMemsetAsync(deg, 0, N_NODES * sizeof(int), stream);
    prep<<<dim3(1024, 3), 256, 0, stream>>>(x, xb, wp, wb, ei, deg);
    scan1<<<NB_SCAN, 256, 0, stream>>>(deg, off, bsum);
    scan2<<<1, 256, 0, stream>>>(bsum, boff);
    scan3<<<NB_SCAN, 256, 0, stream>>>(off, boff, gcur);

    // ---------------- Layer 1 (gemm + pass-A binning fused) ----------------
    gemm1_scatter<<<GEMM_BLKS + SCAT_BLKS, 256, 0, stream>>>(
        xb, wb, bq1, bk1, bv1, bs1, qb, kvb, sb, ei, off, gcur, pairs);
    passB<<<NBK, 256, 0, stream>>>(off, pairs, csr);
    agg_csr<4, true, bf16><<<aggGrid, 256, 0, stream>>>(off, csr, qb,
                                                        (const unsigned int*)kvb, sb, hb);

    // ---------------- Layer 2 ----------------
    gemm2<<<GEMM_BLKS, 256, 0, stream>>>(hb, wb + 32768, bq2, bk2, bv2, bs2,
                                         qb, kvb, sb);
    agg_csr<1, false, float><<<aggGrid, 256, 0, stream>>>(off, csr, qb,
                                                          (const unsigned int*)kvb, sb,
                                                          (float*)d_out);
}

// Round 9
// 279.499 us; speedup vs baseline: 1.2298x; 1.0770x over previous
//
#include <hip/hip_runtime.h>
#include <hip/hip_bf16.h>

// ROUND 25. r24 WIN (301.0, agg 51.5us x2): DPP reduce confirmed chain theory;
// agg now VALU-THROUGHPUT-bound (VALUBusy 84-86%, HBM 23%, Mfma 0).
// Change (agg only): 4 edge-slots/wave x 16 lanes/slot x 4 dims/lane.
//  - kv gather: 1 dwordx4 per slot (same bytes/lines as before)
//  - QK: 4 fma/lane, amortized x4 edges; reduce: 2 quad_perm DPP (H=4),
//    +row_ror 4/8 (H=1); exp2: 1 instr / 4 edges
//  - epilogue: cross-slot shfl_xor(16,32) on 5 regs per node
//  ~7 wave-instr/edge vs ~13+ -> ~2x VALU cut on top dispatch.
// Predict: agg 51.5 -> 33-38us each, VALUBusy stays 75-85%, FETCH ~81MB
// unchanged, total 301 -> ~270-278. If agg flat: VALU model wrong.

#define N_NODES 50000
#define N_EDGES 800000
#define NB_SCAN 196   // ceil(50000/256)
#define NPAD    50048 // allocation pad (>= 1563*32 = 50016)
#define GEMM_BLKS 1563 // ceil(50000/32), 32-row tiles
#define EPB 2048       // edges per scatter block
#define SCAT_BLKS 391  // ceil(800000/2048)
#define NBK 196        // buckets of 256 nodes (dst>>8)
#define CURSTRIDE 16   // one cursor per 64B line

using bf16 = __hip_bfloat16;
typedef __attribute__((ext_vector_type(8))) short bf16x8;
typedef __attribute__((ext_vector_type(4))) float f32x4;
typedef __attribute__((ext_vector_type(4))) unsigned int u32x4;
typedef __attribute__((ext_vector_type(2))) unsigned int u32x2;

__device__ __forceinline__ float b2f(unsigned short u) {
    unsigned int x = ((unsigned int)u) << 16;
    return __builtin_bit_cast(float, x);
}
__device__ __forceinline__ float lo_f(unsigned int u) {
    return __builtin_bit_cast(float, u << 16);
}
__device__ __forceinline__ float hi_f(unsigned int u) {
    return __builtin_bit_cast(float, u & 0xffff0000u);
}
__device__ __forceinline__ short f2b(float f) {
    return (short)__builtin_bit_cast(unsigned short, __float2bfloat16(f));
}

// DPP add helpers. quad_perm 0xB1=[1,0,3,2] (xor1), 0x4E=[2,3,0,1] (xor2);
// row_ror 0x124/0x128 verified on HW in r24.
template <int CTRL>
__device__ __forceinline__ float dadd(float p) {
    int vi = __builtin_bit_cast(int, p);
    int mv = __builtin_amdgcn_update_dpp(vi, vi, CTRL, 0xF, 0xF, false);
    return p + __builtin_bit_cast(float, mv);
}
// per-slot (16-lane row) reduce: H=4 -> quad sum (head); H=1 -> full row sum
template <int H>
__device__ __forceinline__ float edge_reduce(float p) {
    p = dadd<0xB1>(p);
    p = dadd<0x4E>(p);
    if constexpr (H == 1) {
        p = dadd<0x124>(p);  // row_ror:4
        p = dadd<0x128>(p);  // row_ror:8
    }
    return p;
}

struct WPtrs { const float* p[8]; };

// ---------------- fused prep: conv_x / conv_w / hist ----------------
__global__ __launch_bounds__(256) void prep(const float* __restrict__ x,
                                            bf16* __restrict__ xb,
                                            WPtrs wp, bf16* __restrict__ wb,
                                            const int* __restrict__ ei,
                                            int* __restrict__ deg) {
    const int gs = gridDim.x * 256;
    const int t0 = blockIdx.x * 256 + threadIdx.x;
    if (blockIdx.y == 0) {
        // vectorized: 8 elems/iter (2x float4 load, 1x 16B store)
        for (int i = t0; i < N_NODES * 16; i += gs) {
            const float* px = x + (size_t)i * 8;
            f32x4 v0 = *(const f32x4*)px;
            f32x4 v1 = *(const f32x4*)(px + 4);
            bf16x8 o;
#pragma unroll
            for (int q = 0; q < 4; ++q) {
                o[q]     = f2b(v0[q]);
                o[q + 4] = f2b(v1[q]);
            }
            *(bf16x8*)(xb + (size_t)i * 8) = o;
        }
    } else if (blockIdx.y == 1) {
        for (int i = t0; i < 49152; i += gs) {
            int y, o;
            if (i < 32768) { y = i >> 13; o = i & 8191; }
            else { y = 4 + ((i - 32768) >> 12); o = (i - 32768) & 4095; }
            wb[i] = __float2bfloat16(wp.p[y][o]);
        }
    } else {
        for (int e = t0; e < N_EDGES; e += gs)
            atomicAdd(&deg[ei[N_EDGES + e]], 1);
    }
}

// ------------- MFMA GEMM body (MR*16-row tile, 4 weight mats) -------------
template <int K, int MR>
__device__ __forceinline__ void gemm_body(
    int blk, int tid,
    const bf16* __restrict__ A, const bf16* __restrict__ wb,
    const float* __restrict__ bq, const float* __restrict__ bk,
    const float* __restrict__ bv, const float* __restrict__ bs,
    bf16* __restrict__ qb, bf16* __restrict__ kvb, bf16* __restrict__ sb) {
    const int wave = tid >> 6;
    const int lane = tid & 63;
    const int row0 = blk * (MR * 16);
    const int m  = lane & 15;
    const int kg = lane >> 4;
    const bf16* W = wb + (size_t)wave * 64 * K;

    f32x4 acc[MR][4];
#pragma unroll
    for (int i = 0; i < MR; ++i)
#pragma unroll
        for (int j = 0; j < 4; ++j) acc[i][j] = (f32x4){0.f, 0.f, 0.f, 0.f};

#pragma unroll
    for (int k0 = 0; k0 < K; k0 += 32) {
        bf16x8 a[MR], b[4];
#pragma unroll
        for (int i = 0; i < MR; ++i)
            a[i] = *(const bf16x8*)(A + (size_t)(row0 + i * 16 + m) * K + k0 + kg * 8);
#pragma unroll
        for (int j = 0; j < 4; ++j)
            b[j] = *(const bf16x8*)(W + (size_t)(j * 16 + m) * K + k0 + kg * 8);
#pragma unroll
        for (int i = 0; i < MR; ++i)
#pragma unroll
            for (int j = 0; j < 4; ++j)
                acc[i][j] = __builtin_amdgcn_mfma_f32_16x16x32_bf16(a[i], b[j], acc[i][j], 0, 0, 0);
    }

    const int crow = (lane >> 4) * 4;
    const int ccol = lane & 15;
    const float* B = (wave == 0) ? bq : (wave == 1) ? bk : (wave == 2) ? bv : bs;
    float bias[4];
#pragma unroll
    for (int j = 0; j < 4; ++j) bias[j] = B[j * 16 + ccol];

#pragma unroll
    for (int i = 0; i < MR; ++i)
#pragma unroll
        for (int r = 0; r < 4; ++r) {
            int gr = row0 + i * 16 + crow + r;
            if (gr >= N_NODES) continue;
#pragma unroll
            for (int j = 0; j < 4; ++j) {
                float val = acc[i][j][r] + bias[j];
                size_t idx = (size_t)gr * 64 + j * 16 + ccol;
                if (wave == 0) qb[idx] = __float2bfloat16(val);
                else if (wave == 1) kvb[idx * 2] = __float2bfloat16(val);
                else if (wave == 2) kvb[idx * 2 + 1] = __float2bfloat16(val);
                else sb[idx] = __float2bfloat16(val);
            }
        }
}

// layer-1 GEMM + pass-A LDS-binned scatter fused.
__global__ __launch_bounds__(256) void gemm1_scatter(
    const bf16* __restrict__ A, const bf16* __restrict__ wb,
    const float* __restrict__ bq, const float* __restrict__ bk,
    const float* __restrict__ bv, const float* __restrict__ bs,
    bf16* __restrict__ qb, bf16* __restrict__ kvb, bf16* __restrict__ sb,
    const int* __restrict__ ei, const int* __restrict__ off,
    int* __restrict__ gcur, unsigned int* __restrict__ pairs) {
    __shared__ int hist[256];
    __shared__ int sm[256];
    __shared__ int obs[NBK];
    __shared__ unsigned int stage[EPB];

    if (blockIdx.x < GEMM_BLKS) {
        gemm_body<128, 2>(blockIdx.x, threadIdx.x, A, wb, bq, bk, bv, bs, qb, kvb, sb);
        return;
    }
    const int t = threadIdx.x;
    const int e0 = (blockIdx.x - GEMM_BLKS) * EPB;
    hist[t] = 0;
    __syncthreads();

    // per-edge: bucket + within-bucket rank via LDS atomics
    unsigned int pk[8];
    int bb[8], rr[8];
#pragma unroll
    for (int u = 0; u < 8; ++u) {
        const int e = e0 + u * 256 + t;
        if (e < N_EDGES) {
            int d  = ei[N_EDGES + e];
            int sv = ei[e];
            pk[u] = ((unsigned int)d << 16) | (unsigned int)sv;
            bb[u] = d >> 8;
            rr[u] = atomicAdd(&hist[bb[u]], 1);
        } else {
            bb[u] = -1;
        }
    }
    __syncthreads();

    // block-wide inclusive scan of hist (256 entries, Hillis-Steele)
    int hv = hist[t];
    sm[t] = hv;
    __syncthreads();
    for (int st = 1; st < 256; st <<= 1) {
        int tmp = (t >= st) ? sm[t - st] : 0;
        __syncthreads();
        sm[t] += tmp;
        __syncthreads();
    }
    const int total = sm[255];

    // one global reservation per non-empty bucket
    if (t < NBK && hv > 0) {
        int g = atomicAdd(&gcur[t * CURSTRIDE], hv);
        obs[t] = off[t << 8] + g - (sm[t] - hv);  // global base minus local run start
    }
    __syncthreads();

    // bin into LDS staging (bucket-sorted)
#pragma unroll
    for (int u = 0; u < 8; ++u)
        if (bb[u] >= 0) stage[(sm[bb[u]] - hist[bb[u]]) + rr[u]] = pk[u];
    __syncthreads();

    // copy-out: consecutive j within a bucket run -> contiguous global stores
    for (int j = t; j < total; j += 256) {
        unsigned int pr = stage[j];
        int b = pr >> 24;  // dst>>8
        pairs[obs[b] + j] = pr;
    }
}

// Pass B: one block per bucket (256 nodes). off-window in LDS, LDS-rank,
// dense stores into the bucket's contiguous csr region.
__global__ __launch_bounds__(256) void passB(const int* __restrict__ off,
                                             const unsigned int* __restrict__ pairs,
                                             int* __restrict__ csr) {
    __shared__ int lcnt[256];
    __shared__ int loff[256];
    const int b = blockIdx.x;
    const int n0 = b << 8;
    const int nend = (n0 + 256 < N_NODES) ? n0 + 256 : N_NODES;
    lcnt[threadIdx.x] = 0;
    if (n0 + threadIdx.x < nend) loff[threadIdx.x] = off[n0 + threadIdx.x];
    const int p0 = off[n0];
    const int p1 = off[nend];
    __syncthreads();
    for (int j = p0 + threadIdx.x; j < p1; j += 256) {
        unsigned int pr = pairs[j];
        int d  = (int)(pr >> 16);
        int sv = (int)(pr & 0xffffu);
        int r = atomicAdd(&lcnt[d - n0], 1);
        csr[loff[d - n0] + r] = sv;
    }
}

__global__ __launch_bounds__(256) void gemm2(
    const bf16* __restrict__ A, const bf16* __restrict__ wb,
    const float* __restrict__ bq, const float* __restrict__ bk,
    const float* __restrict__ bv, const float* __restrict__ bs,
    bf16* __restrict__ qb, bf16* __restrict__ kvb, bf16* __restrict__ sb) {
    gemm_body<64, 2>(blockIdx.x, threadIdx.x, A, wb, bq, bk, bv, bs, qb, kvb, sb);
}

// ---------------- CSR scan ----------------
__global__ __launch_bounds__(256) void scan1(const int* __restrict__ deg,
                                             int* __restrict__ off,
                                             int* __restrict__ bsum) {
    __shared__ int sm[256];
    int i = blockIdx.x * 256 + threadIdx.x;
    int v = (i < N_NODES) ? deg[i] : 0;
    sm[threadIdx.x] = v;
    __syncthreads();
    for (int st = 1; st < 256; st <<= 1) {
        int t = (threadIdx.x >= (unsigned)st) ? sm[threadIdx.x - st] : 0;
        __syncthreads();
        sm[threadIdx.x] += t;
        __syncthreads();
    }
    if (i < N_NODES) off[i] = sm[threadIdx.x] - v;
    if (threadIdx.x == 255) bsum[blockIdx.x] = sm[255];
}

__global__ __launch_bounds__(256) void scan2(const int* __restrict__ bsum,
                                             int* __restrict__ boff) {
    __shared__ int sm[256];
    int b = threadIdx.x;
    int v = (b < NB_SCAN) ? bsum[b] : 0;
    sm[b] = v;
    __syncthreads();
    for (int st = 1; st < 256; st <<= 1) {
        int t = (b >= st) ? sm[b - st] : 0;
        __syncthreads();
        sm[b] += t;
        __syncthreads();
    }
    if (b < NB_SCAN) boff[b] = sm[b] - v;
    if (b == 255) boff[NB_SCAN] = sm[255];
}

__global__ __launch_bounds__(256) void scan3(int* __restrict__ off,
                                             const int* __restrict__ boff,
                                             int* __restrict__ gcur) {
    int i = blockIdx.x * 256 + threadIdx.x;
    if (i < N_NODES) off[i] = off[i] + boff[blockIdx.x];
    if (i == 0) off[N_NODES] = boff[NB_SCAN];
    if (i < NBK * CURSTRIDE) gcur[i] = 0;
}

// ---- Aggregation: 4 edge-slots/wave, 16 lanes/slot, 4 dims/lane ----
// lane = slot*16 + m; lane owns dims 4m..4m+3 of its slot's edge.
// H=4: head h = dims 16h..16h+15 = quad m in {4h..4h+3} -> quad_perm reduce.
// H=1: full 16-lane row reduce. Cross-slot combine via shfl_xor(16,32).
template <int H, bool RELU, typename OT>
__global__ __launch_bounds__(256) void agg_csr(const int* __restrict__ off,
                                               const int* __restrict__ csr_src,
                                               const bf16* __restrict__ qb,
                                               const unsigned int* __restrict__ kvu,
                                               const bf16* __restrict__ sb,
                                               OT* __restrict__ out) {
    const float SC = ((H == 4) ? 0.25f : 0.125f) * 1.4426950408889634f;
    const int lane = threadIdx.x & 63;
    const int slot = lane >> 4;
    const int m    = lane & 15;
    const int n = (blockIdx.x * 256 + threadIdx.x) >> 6;
    if (n >= N_NODES) return;

    // q dims 4m..4m+3 (8B, broadcast across slots)
    const unsigned int* qp = (const unsigned int*)qb + (size_t)n * 32 + m * 2;
    const unsigned int q01 = qp[0], q23 = qp[1];
    const float qf0 = lo_f(q01), qf1 = hi_f(q01);
    const float qf2 = lo_f(q23), qf3 = hi_f(q23);

    float a0 = 0.f, a1 = 0.f, a2 = 0.f, a3 = 0.f, ds = 0.f;
    int jb = off[n];
    const int j1 = off[n + 1];
    const unsigned int mb = (unsigned)m * 4;

    // main: 2 batches (8 edges) per iter, no masking
    for (; jb + 8 <= j1; jb += 8) {
        const unsigned s0 = (unsigned)csr_src[jb + slot];
        const unsigned s1 = (unsigned)csr_src[jb + 4 + slot];
        u32x4 w0 = *(const u32x4*)(kvu + (((size_t)s0) << 6) + mb);
        u32x4 w1 = *(const u32x4*)(kvu + (((size_t)s1) << 6) + mb);
        float p0 = qf0 * lo_f(w0[0]);
        p0 = fmaf(qf1, lo_f(w0[1]), p0);
        p0 = fmaf(qf2, lo_f(w0[2]), p0);
        p0 = fmaf(qf3, lo_f(w0[3]), p0);
        float p1 = qf0 * lo_f(w1[0]);
        p1 = fmaf(qf1, lo_f(w1[1]), p1);
        p1 = fmaf(qf2, lo_f(w1[2]), p1);
        p1 = fmaf(qf3, lo_f(w1[3]), p1);
        p0 = edge_reduce<H>(p0);
        p1 = edge_reduce<H>(p1);
        const float e0 = exp2f(p0 * SC);
        const float e1 = exp2f(p1 * SC);
        a0 = fmaf(e0, hi_f(w0[0]), a0); a0 = fmaf(e1, hi_f(w1[0]), a0);
        a1 = fmaf(e0, hi_f(w0[1]), a1); a1 = fmaf(e1, hi_f(w1[1]), a1);
        a2 = fmaf(e0, hi_f(w0[2]), a2); a2 = fmaf(e1, hi_f(w1[2]), a2);
        a3 = fmaf(e0, hi_f(w0[3]), a3); a3 = fmaf(e1, hi_f(w1[3]), a3);
        ds += e0 + e1;
    }
    // tail: masked 4-edge batches
    for (; jb < j1; jb += 4) {
        int jc = jb + slot;
        const bool valid = jc < j1;
        if (!valid) jc = j1 - 1;  // valid address (j1>=1 here)
        const unsigned s0 = (unsigned)csr_src[jc];
        u32x4 w0 = *(const u32x4*)(kvu + (((size_t)s0) << 6) + mb);
        float p0 = qf0 * lo_f(w0[0]);
        p0 = fmaf(qf1, lo_f(w0[1]), p0);
        p0 = fmaf(qf2, lo_f(w0[2]), p0);
        p0 = fmaf(qf3, lo_f(w0[3]), p0);
        p0 = edge_reduce<H>(p0);
        const float e0 = valid ? exp2f(p0 * SC) : 0.f;
        a0 = fmaf(e0, hi_f(w0[0]), a0);
        a1 = fmaf(e0, hi_f(w0[1]), a1);
        a2 = fmaf(e0, hi_f(w0[2]), a2);
        a3 = fmaf(e0, hi_f(w0[3]), a3);
        ds += e0;
    }

    // combine across the 4 edge-slots
    a0 += __shfl_xor(a0, 16, 64); a0 += __shfl_xor(a0, 32, 64);
    a1 += __shfl_xor(a1, 16, 64); a1 += __shfl_xor(a1, 32, 64);
    a2 += __shfl_xor(a2, 16, 64); a2 += __shfl_xor(a2, 32, 64);
    a3 += __shfl_xor(a3, 16, 64); a3 += __shfl_xor(a3, 32, 64);
    ds += __shfl_xor(ds, 16, 64); ds += __shfl_xor(ds, 32, 64);

    if (lane < 16) {
        const float inv = (ds != 0.f) ? 1.f / ds : 0.f;
        const unsigned int* sp = (const unsigned int*)sb + (size_t)n * 32 + m * 2;
        const unsigned int s01 = sp[0], s23 = sp[1];
        float v0 = fmaf(a0, inv, lo_f(s01));
        float v1 = fmaf(a1, inv, hi_f(s01));
        float v2 = fmaf(a2, inv, lo_f(s23));
        float v3 = fmaf(a3, inv, hi_f(s23));
        if (RELU) {
            v0 = fmaxf(v0, 0.f); v1 = fmaxf(v1, 0.f);
            v2 = fmaxf(v2, 0.f); v3 = fmaxf(v3, 0.f);
        }
        if constexpr (__hip_internal::is_same<OT, bf16>::value) {
            u32x2 o;
            o[0] = (unsigned)(unsigned short)f2b(v0) |
                   ((unsigned)(unsigned short)f2b(v1) << 16);
            o[1] = (unsigned)(unsigned short)f2b(v2) |
                   ((unsigned)(unsigned short)f2b(v3) << 16);
            *(u32x2*)((unsigned int*)out + (size_t)n * 32 + m * 2) = o;  // hb
        } else {
            f32x4 o = (f32x4){v0, v1, v2, v3};
            __builtin_nontemporal_store(o, (f32x4*)((float*)out + (size_t)n * 64 + mb));
        }
    }
}

extern "C" void kernel_launch(void* const* d_in, const int* in_sizes, int n_in,
                              void* d_out, int out_size, void* d_ws, size_t ws_size,
                              hipStream_t stream) {
    const float* x  = (const float*)d_in[0];
    const int*   ei = (const int*)d_in[1];
    const float* bq1 = (const float*)d_in[3];
    const float* bk1 = (const float*)d_in[5];
    const float* bv1 = (const float*)d_in[7];
    const float* bs1 = (const float*)d_in[9];
    const float* bq2 = (const float*)d_in[11];
    const float* bk2 = (const float*)d_in[13];
    const float* bv2 = (const float*)d_in[15];
    const float* bs2 = (const float*)d_in[17];

    WPtrs wp;
    wp.p[0] = (const float*)d_in[2];
    wp.p[1] = (const float*)d_in[4];
    wp.p[2] = (const float*)d_in[6];
    wp.p[3] = (const float*)d_in[8];
    wp.p[4] = (const float*)d_in[10];
    wp.p[5] = (const float*)d_in[12];
    wp.p[6] = (const float*)d_in[14];
    wp.p[7] = (const float*)d_in[16];

    const size_t N = N_NODES;
    bf16* xb  = (bf16*)d_ws;                 // NPAD*128
    bf16* hb  = xb + (size_t)NPAD * 128;     // NPAD*64
    bf16* qb  = hb + (size_t)NPAD * 64;      // N*64
    bf16* kvb = qb + N * 64;                 // 2*N*64 interleaved
    bf16* wb  = kvb + 2 * N * 64;            // 49152
    bf16* sb  = wb + 49152;                  // N*64 (bf16)
    int* deg  = (int*)(sb + N * 64);         // N
    int* off  = deg + N_NODES;               // N+1
    int* gcur = off + N_NODES + 1;           // NBK*CURSTRIDE
    int* bsum = gcur + N_NODES;              // NB_SCAN
    int* boff = bsum + NB_SCAN;              // NB_SCAN+1
    int* csr  = boff + NB_SCAN + 1;          // E
    unsigned int* pairs = (unsigned int*)(csr + N_EDGES); // E

    const int aggGrid = (N_NODES * 64 + 255) / 256;

    // ---------------- prep + CSR ----------------
    hipMemsetAsync(deg, 0, N_NODES * sizeof(int), stream);
    prep<<<dim3(1024, 3), 256, 0, stream>>>(x, xb, wp, wb, ei, deg);
    scan1<<<NB_SCAN, 256, 0, stream>>>(deg, off, bsum);
    scan2<<<1, 256, 0, stream>>>(bsum, boff);
    scan3<<<NB_SCAN, 256, 0, stream>>>(off, boff, gcur);

    // ---------------- Layer 1 (gemm + pass-A binning fused) ----------------
    gemm1_scatter<<<GEMM_BLKS + SCAT_BLKS, 256, 0, stream>>>(
        xb, wb, bq1, bk1, bv1, bs1, qb, kvb, sb, ei, off, gcur, pairs);
    passB<<<NBK, 256, 0, stream>>>(off, pairs, csr);
    agg_csr<4, true, bf16><<<aggGrid, 256, 0, stream>>>(off, csr, qb,
                                                        (const unsigned int*)kvb, sb, hb);

    // ---------------- Layer 2 ----------------
    gemm2<<<GEMM_BLKS, 256, 0, stream>>>(hb, wb + 32768, bq2, bk2, bv2, bs2,
                                         qb, kvb, sb);
    agg_csr<1, false, float><<<aggGrid, 256, 0, stream>>>(off, csr, qb,
                                                          (const unsigned int*)kvb, sb,
                                                          (float*)d_out);
}

// Round 10
// 278.894 us; speedup vs baseline: 1.2325x; 1.0022x over previous
//
#include <hip/hip_runtime.h>
#include <hip/hip_bf16.h>

// ROUND 26. r25 WIN (279.5): slot-parallel agg confirmed VALU theory (agg
// <44us, off top-5). Top-5 now = harness's 268MB workspace re-poison fill
// (~45us/iter, fixed). Per-kernel visibility lost below 44us cutoff.
// Changes:
//  1) scatter blocks FIRST in gemm1_scatter grid: with ~1536 resident block
//     slots, scatter previously started only after the first gemm wave
//     drained -> exposed tail. Now overlaps MFMA from t=0.
//  2) scan2 folded into scan3 (each block reduces bsum[0..b) itself): -1
//     dispatch.
//  3) csr int->u16 (src<65536): -4.8MB across passB write + 2 agg reads.
// Predict: total 279.5 -> ~264-271. If flat: scatter-first theory wrong ->
// split scatter out to measure.

#define N_NODES 50000
#define N_EDGES 800000
#define NB_SCAN 196   // ceil(50000/256)
#define NPAD    50048 // allocation pad (>= 1563*32 = 50016)
#define GEMM_BLKS 1563 // ceil(50000/32), 32-row tiles
#define EPB 2048       // edges per scatter block
#define SCAT_BLKS 391  // ceil(800000/2048)
#define NBK 196        // buckets of 256 nodes (dst>>8)
#define CURSTRIDE 16   // one cursor per 64B line

using bf16 = __hip_bfloat16;
typedef __attribute__((ext_vector_type(8))) short bf16x8;
typedef __attribute__((ext_vector_type(4))) float f32x4;
typedef __attribute__((ext_vector_type(4))) unsigned int u32x4;
typedef __attribute__((ext_vector_type(2))) unsigned int u32x2;

__device__ __forceinline__ float b2f(unsigned short u) {
    unsigned int x = ((unsigned int)u) << 16;
    return __builtin_bit_cast(float, x);
}
__device__ __forceinline__ float lo_f(unsigned int u) {
    return __builtin_bit_cast(float, u << 16);
}
__device__ __forceinline__ float hi_f(unsigned int u) {
    return __builtin_bit_cast(float, u & 0xffff0000u);
}
__device__ __forceinline__ short f2b(float f) {
    return (short)__builtin_bit_cast(unsigned short, __float2bfloat16(f));
}

// DPP add helpers. quad_perm 0xB1=[1,0,3,2] (xor1), 0x4E=[2,3,0,1] (xor2);
// row_ror 0x124/0x128 verified on HW in r24.
template <int CTRL>
__device__ __forceinline__ float dadd(float p) {
    int vi = __builtin_bit_cast(int, p);
    int mv = __builtin_amdgcn_update_dpp(vi, vi, CTRL, 0xF, 0xF, false);
    return p + __builtin_bit_cast(float, mv);
}
// per-slot (16-lane row) reduce: H=4 -> quad sum (head); H=1 -> full row sum
template <int H>
__device__ __forceinline__ float edge_reduce(float p) {
    p = dadd<0xB1>(p);
    p = dadd<0x4E>(p);
    if constexpr (H == 1) {
        p = dadd<0x124>(p);  // row_ror:4
        p = dadd<0x128>(p);  // row_ror:8
    }
    return p;
}

struct WPtrs { const float* p[8]; };

// ---------------- fused prep: conv_x / conv_w / hist ----------------
__global__ __launch_bounds__(256) void prep(const float* __restrict__ x,
                                            bf16* __restrict__ xb,
                                            WPtrs wp, bf16* __restrict__ wb,
                                            const int* __restrict__ ei,
                                            int* __restrict__ deg) {
    const int gs = gridDim.x * 256;
    const int t0 = blockIdx.x * 256 + threadIdx.x;
    if (blockIdx.y == 0) {
        // vectorized: 8 elems/iter (2x float4 load, 1x 16B store)
        for (int i = t0; i < N_NODES * 16; i += gs) {
            const float* px = x + (size_t)i * 8;
            f32x4 v0 = *(const f32x4*)px;
            f32x4 v1 = *(const f32x4*)(px + 4);
            bf16x8 o;
#pragma unroll
            for (int q = 0; q < 4; ++q) {
                o[q]     = f2b(v0[q]);
                o[q + 4] = f2b(v1[q]);
            }
            *(bf16x8*)(xb + (size_t)i * 8) = o;
        }
    } else if (blockIdx.y == 1) {
        for (int i = t0; i < 49152; i += gs) {
            int y, o;
            if (i < 32768) { y = i >> 13; o = i & 8191; }
            else { y = 4 + ((i - 32768) >> 12); o = (i - 32768) & 4095; }
            wb[i] = __float2bfloat16(wp.p[y][o]);
        }
    } else {
        for (int e = t0; e < N_EDGES; e += gs)
            atomicAdd(&deg[ei[N_EDGES + e]], 1);
    }
}

// ------------- MFMA GEMM body (MR*16-row tile, 4 weight mats) -------------
template <int K, int MR>
__device__ __forceinline__ void gemm_body(
    int blk, int tid,
    const bf16* __restrict__ A, const bf16* __restrict__ wb,
    const float* __restrict__ bq, const float* __restrict__ bk,
    const float* __restrict__ bv, const float* __restrict__ bs,
    bf16* __restrict__ qb, bf16* __restrict__ kvb, bf16* __restrict__ sb) {
    const int wave = tid >> 6;
    const int lane = tid & 63;
    const int row0 = blk * (MR * 16);
    const int m  = lane & 15;
    const int kg = lane >> 4;
    const bf16* W = wb + (size_t)wave * 64 * K;

    f32x4 acc[MR][4];
#pragma unroll
    for (int i = 0; i < MR; ++i)
#pragma unroll
        for (int j = 0; j < 4; ++j) acc[i][j] = (f32x4){0.f, 0.f, 0.f, 0.f};

#pragma unroll
    for (int k0 = 0; k0 < K; k0 += 32) {
        bf16x8 a[MR], b[4];
#pragma unroll
        for (int i = 0; i < MR; ++i)
            a[i] = *(const bf16x8*)(A + (size_t)(row0 + i * 16 + m) * K + k0 + kg * 8);
#pragma unroll
        for (int j = 0; j < 4; ++j)
            b[j] = *(const bf16x8*)(W + (size_t)(j * 16 + m) * K + k0 + kg * 8);
#pragma unroll
        for (int i = 0; i < MR; ++i)
#pragma unroll
            for (int j = 0; j < 4; ++j)
                acc[i][j] = __builtin_amdgcn_mfma_f32_16x16x32_bf16(a[i], b[j], acc[i][j], 0, 0, 0);
    }

    const int crow = (lane >> 4) * 4;
    const int ccol = lane & 15;
    const float* B = (wave == 0) ? bq : (wave == 1) ? bk : (wave == 2) ? bv : bs;
    float bias[4];
#pragma unroll
    for (int j = 0; j < 4; ++j) bias[j] = B[j * 16 + ccol];

#pragma unroll
    for (int i = 0; i < MR; ++i)
#pragma unroll
        for (int r = 0; r < 4; ++r) {
            int gr = row0 + i * 16 + crow + r;
            if (gr >= N_NODES) continue;
#pragma unroll
            for (int j = 0; j < 4; ++j) {
                float val = acc[i][j][r] + bias[j];
                size_t idx = (size_t)gr * 64 + j * 16 + ccol;
                if (wave == 0) qb[idx] = __float2bfloat16(val);
                else if (wave == 1) kvb[idx * 2] = __float2bfloat16(val);
                else if (wave == 2) kvb[idx * 2 + 1] = __float2bfloat16(val);
                else sb[idx] = __float2bfloat16(val);
            }
        }
}

// layer-1 GEMM + pass-A LDS-binned scatter fused. SCATTER BLOCKS FIRST so
// their long-latency atomics/gathers co-run with MFMA gemm blocks from t=0.
__global__ __launch_bounds__(256) void gemm1_scatter(
    const bf16* __restrict__ A, const bf16* __restrict__ wb,
    const float* __restrict__ bq, const float* __restrict__ bk,
    const float* __restrict__ bv, const float* __restrict__ bs,
    bf16* __restrict__ qb, bf16* __restrict__ kvb, bf16* __restrict__ sb,
    const int* __restrict__ ei, const int* __restrict__ off,
    int* __restrict__ gcur, unsigned int* __restrict__ pairs) {
    __shared__ int hist[256];
    __shared__ int sm[256];
    __shared__ int obs[NBK];
    __shared__ unsigned int stage[EPB];

    if (blockIdx.x >= SCAT_BLKS) {
        gemm_body<128, 2>(blockIdx.x - SCAT_BLKS, threadIdx.x, A, wb,
                          bq, bk, bv, bs, qb, kvb, sb);
        return;
    }
    const int t = threadIdx.x;
    const int e0 = blockIdx.x * EPB;
    hist[t] = 0;
    __syncthreads();

    // per-edge: bucket + within-bucket rank via LDS atomics
    unsigned int pk[8];
    int bb[8], rr[8];
#pragma unroll
    for (int u = 0; u < 8; ++u) {
        const int e = e0 + u * 256 + t;
        if (e < N_EDGES) {
            int d  = ei[N_EDGES + e];
            int sv = ei[e];
            pk[u] = ((unsigned int)d << 16) | (unsigned int)sv;
            bb[u] = d >> 8;
            rr[u] = atomicAdd(&hist[bb[u]], 1);
        } else {
            bb[u] = -1;
        }
    }
    __syncthreads();

    // block-wide inclusive scan of hist (256 entries, Hillis-Steele)
    int hv = hist[t];
    sm[t] = hv;
    __syncthreads();
    for (int st = 1; st < 256; st <<= 1) {
        int tmp = (t >= st) ? sm[t - st] : 0;
        __syncthreads();
        sm[t] += tmp;
        __syncthreads();
    }
    const int total = sm[255];

    // one global reservation per non-empty bucket
    if (t < NBK && hv > 0) {
        int g = atomicAdd(&gcur[t * CURSTRIDE], hv);
        obs[t] = off[t << 8] + g - (sm[t] - hv);  // global base minus local run start
    }
    __syncthreads();

    // bin into LDS staging (bucket-sorted)
#pragma unroll
    for (int u = 0; u < 8; ++u)
        if (bb[u] >= 0) stage[(sm[bb[u]] - hist[bb[u]]) + rr[u]] = pk[u];
    __syncthreads();

    // copy-out: consecutive j within a bucket run -> contiguous global stores
    for (int j = t; j < total; j += 256) {
        unsigned int pr = stage[j];
        int b = pr >> 24;  // dst>>8
        pairs[obs[b] + j] = pr;
    }
}

// Pass B: one block per bucket (256 nodes). off-window in LDS, LDS-rank,
// dense u16 stores into the bucket's contiguous csr region.
__global__ __launch_bounds__(256) void passB(const int* __restrict__ off,
                                             const unsigned int* __restrict__ pairs,
                                             unsigned short* __restrict__ csr) {
    __shared__ int lcnt[256];
    __shared__ int loff[256];
    const int b = blockIdx.x;
    const int n0 = b << 8;
    const int nend = (n0 + 256 < N_NODES) ? n0 + 256 : N_NODES;
    lcnt[threadIdx.x] = 0;
    if (n0 + threadIdx.x < nend) loff[threadIdx.x] = off[n0 + threadIdx.x];
    const int p0 = off[n0];
    const int p1 = off[nend];
    __syncthreads();
    for (int j = p0 + threadIdx.x; j < p1; j += 256) {
        unsigned int pr = pairs[j];
        int d  = (int)(pr >> 16);
        int sv = (int)(pr & 0xffffu);
        int r = atomicAdd(&lcnt[d - n0], 1);
        csr[loff[d - n0] + r] = (unsigned short)sv;
    }
}

__global__ __launch_bounds__(256) void gemm2(
    const bf16* __restrict__ A, const bf16* __restrict__ wb,
    const float* __restrict__ bq, const float* __restrict__ bk,
    const float* __restrict__ bv, const float* __restrict__ bs,
    bf16* __restrict__ qb, bf16* __restrict__ kvb, bf16* __restrict__ sb) {
    gemm_body<64, 2>(blockIdx.x, threadIdx.x, A, wb, bq, bk, bv, bs, qb, kvb, sb);
}

// ---------------- CSR scan (scan2 folded into scan3) ----------------
__global__ __launch_bounds__(256) void scan1(const int* __restrict__ deg,
                                             int* __restrict__ off,
                                             int* __restrict__ bsum) {
    __shared__ int sm[256];
    int i = blockIdx.x * 256 + threadIdx.x;
    int v = (i < N_NODES) ? deg[i] : 0;
    sm[threadIdx.x] = v;
    __syncthreads();
    for (int st = 1; st < 256; st <<= 1) {
        int t = (threadIdx.x >= (unsigned)st) ? sm[threadIdx.x - st] : 0;
        __syncthreads();
        sm[threadIdx.x] += t;
        __syncthreads();
    }
    if (i < N_NODES) off[i] = sm[threadIdx.x] - v;
    if (threadIdx.x == 255) bsum[blockIdx.x] = sm[255];
}

// scan3: each block self-reduces bsum[0..b) (prefix) and bsum[0..NB) (total).
__global__ __launch_bounds__(256) void scan3(int* __restrict__ off,
                                             const int* __restrict__ bsum,
                                             int* __restrict__ gcur) {
    __shared__ int sm[256];
    __shared__ int tm[256];
    const int t = threadIdx.x;
    const int b = blockIdx.x;
    int v = (t < NB_SCAN) ? bsum[t] : 0;
    sm[t] = (t < b) ? v : 0;
    tm[t] = v;
    __syncthreads();
    for (int st = 128; st >= 1; st >>= 1) {
        if (t < st) { sm[t] += sm[t + st]; tm[t] += tm[t + st]; }
        __syncthreads();
    }
    const int pre = sm[0];
    const int i = b * 256 + t;
    if (i < N_NODES) off[i] += pre;
    if (b == NB_SCAN - 1 && t == 0) off[N_NODES] = tm[0];
    if (i < NBK * CURSTRIDE) gcur[i] = 0;
}

// ---- Aggregation: 4 edge-slots/wave, 16 lanes/slot, 4 dims/lane ----
// lane = slot*16 + m; lane owns dims 4m..4m+3 of its slot's edge.
// H=4: head h = dims 16h..16h+15 = quad m in {4h..4h+3} -> quad_perm reduce.
// H=1: full 16-lane row reduce. Cross-slot combine via shfl_xor(16,32).
template <int H, bool RELU, typename OT>
__global__ __launch_bounds__(256) void agg_csr(const int* __restrict__ off,
                                               const unsigned short* __restrict__ csr_src,
                                               const bf16* __restrict__ qb,
                                               const unsigned int* __restrict__ kvu,
                                               const bf16* __restrict__ sb,
                                               OT* __restrict__ out) {
    const float SC = ((H == 4) ? 0.25f : 0.125f) * 1.4426950408889634f;
    const int lane = threadIdx.x & 63;
    const int slot = lane >> 4;
    const int m    = lane & 15;
    const int n = (blockIdx.x * 256 + threadIdx.x) >> 6;
    if (n >= N_NODES) return;

    // q dims 4m..4m+3 (8B, broadcast across slots)
    const unsigned int* qp = (const unsigned int*)qb + (size_t)n * 32 + m * 2;
    const unsigned int q01 = qp[0], q23 = qp[1];
    const float qf0 = lo_f(q01), qf1 = hi_f(q01);
    const float qf2 = lo_f(q23), qf3 = hi_f(q23);

    float a0 = 0.f, a1 = 0.f, a2 = 0.f, a3 = 0.f, ds = 0.f;
    int jb = off[n];
    const int j1 = off[n + 1];
    const unsigned int mb = (unsigned)m * 4;

    // main: 2 batches (8 edges) per iter, no masking
    for (; jb + 8 <= j1; jb += 8) {
        const unsigned s0 = (unsigned)csr_src[jb + slot];
        const unsigned s1 = (unsigned)csr_src[jb + 4 + slot];
        u32x4 w0 = *(const u32x4*)(kvu + (((size_t)s0) << 6) + mb);
        u32x4 w1 = *(const u32x4*)(kvu + (((size_t)s1) << 6) + mb);
        float p0 = qf0 * lo_f(w0[0]);
        p0 = fmaf(qf1, lo_f(w0[1]), p0);
        p0 = fmaf(qf2, lo_f(w0[2]), p0);
        p0 = fmaf(qf3, lo_f(w0[3]), p0);
        float p1 = qf0 * lo_f(w1[0]);
        p1 = fmaf(qf1, lo_f(w1[1]), p1);
        p1 = fmaf(qf2, lo_f(w1[2]), p1);
        p1 = fmaf(qf3, lo_f(w1[3]), p1);
        p0 = edge_reduce<H>(p0);
        p1 = edge_reduce<H>(p1);
        const float e0 = exp2f(p0 * SC);
        const float e1 = exp2f(p1 * SC);
        a0 = fmaf(e0, hi_f(w0[0]), a0); a0 = fmaf(e1, hi_f(w1[0]), a0);
        a1 = fmaf(e0, hi_f(w0[1]), a1); a1 = fmaf(e1, hi_f(w1[1]), a1);
        a2 = fmaf(e0, hi_f(w0[2]), a2); a2 = fmaf(e1, hi_f(w1[2]), a2);
        a3 = fmaf(e0, hi_f(w0[3]), a3); a3 = fmaf(e1, hi_f(w1[3]), a3);
        ds += e0 + e1;
    }
    // tail: masked 4-edge batches
    for (; jb < j1; jb += 4) {
        int jc = jb + slot;
        const bool valid = jc < j1;
        if (!valid) jc = j1 - 1;  // valid address (j1>=1 here)
        const unsigned s0 = (unsigned)csr_src[jc];
        u32x4 w0 = *(const u32x4*)(kvu + (((size_t)s0) << 6) + mb);
        float p0 = qf0 * lo_f(w0[0]);
        p0 = fmaf(qf1, lo_f(w0[1]), p0);
        p0 = fmaf(qf2, lo_f(w0[2]), p0);
        p0 = fmaf(qf3, lo_f(w0[3]), p0);
        p0 = edge_reduce<H>(p0);
        const float e0 = valid ? exp2f(p0 * SC) : 0.f;
        a0 = fmaf(e0, hi_f(w0[0]), a0);
        a1 = fmaf(e0, hi_f(w0[1]), a1);
        a2 = fmaf(e0, hi_f(w0[2]), a2);
        a3 = fmaf(e0, hi_f(w0[3]), a3);
        ds += e0;
    }

    // combine across the 4 edge-slots
    a0 += __shfl_xor(a0, 16, 64); a0 += __shfl_xor(a0, 32, 64);
    a1 += __shfl_xor(a1, 16, 64); a1 += __shfl_xor(a1, 32, 64);
    a2 += __shfl_xor(a2, 16, 64); a2 += __shfl_xor(a2, 32, 64);
    a3 += __shfl_xor(a3, 16, 64); a3 += __shfl_xor(a3, 32, 64);
    ds += __shfl_xor(ds, 16, 64); ds += __shfl_xor(ds, 32, 64);

    if (lane < 16) {
        const float inv = (ds != 0.f) ? 1.f / ds : 0.f;
        const unsigned int* sp = (const unsigned int*)sb + (size_t)n * 32 + m * 2;
        const unsigned int s01 = sp[0], s23 = sp[1];
        float v0 = fmaf(a0, inv, lo_f(s01));
        float v1 = fmaf(a1, inv, hi_f(s01));
        float v2 = fmaf(a2, inv, lo_f(s23));
        float v3 = fmaf(a3, inv, hi_f(s23));
        if (RELU) {
            v0 = fmaxf(v0, 0.f); v1 = fmaxf(v1, 0.f);
            v2 = fmaxf(v2, 0.f); v3 = fmaxf(v3, 0.f);
        }
        if constexpr (__hip_internal::is_same<OT, bf16>::value) {
            u32x2 o;
            o[0] = (unsigned)(unsigned short)f2b(v0) |
                   ((unsigned)(unsigned short)f2b(v1) << 16);
            o[1] = (unsigned)(unsigned short)f2b(v2) |
                   ((unsigned)(unsigned short)f2b(v3) << 16);
            *(u32x2*)((unsigned int*)out + (size_t)n * 32 + m * 2) = o;  // hb
        } else {
            f32x4 o = (f32x4){v0, v1, v2, v3};
            __builtin_nontemporal_store(o, (f32x4*)((float*)out + (size_t)n * 64 + mb));
        }
    }
}

extern "C" void kernel_launch(void* const* d_in, const int* in_sizes, int n_in,
                              void* d_out, int out_size, void* d_ws, size_t ws_size,
                              hipStream_t stream) {
    const float* x  = (const float*)d_in[0];
    const int*   ei = (const int*)d_in[1];
    const float* bq1 = (const float*)d_in[3];
    const float* bk1 = (const float*)d_in[5];
    const float* bv1 = (const float*)d_in[7];
    const float* bs1 = (const float*)d_in[9];
    const float* bq2 = (const float*)d_in[11];
    const float* bk2 = (const float*)d_in[13];
    const float* bv2 = (const float*)d_in[15];
    const float* bs2 = (const float*)d_in[17];

    WPtrs wp;
    wp.p[0] = (const float*)d_in[2];
    wp.p[1] = (const float*)d_in[4];
    wp.p[2] = (const float*)d_in[6];
    wp.p[3] = (const float*)d_in[8];
    wp.p[4] = (const float*)d_in[10];
    wp.p[5] = (const float*)d_in[12];
    wp.p[6] = (const float*)d_in[14];
    wp.p[7] = (const float*)d_in[16];

    const size_t N = N_NODES;
    bf16* xb  = (bf16*)d_ws;                 // NPAD*128
    bf16* hb  = xb + (size_t)NPAD * 128;     // NPAD*64
    bf16* qb  = hb + (size_t)NPAD * 64;      // N*64
    bf16* kvb = qb + N * 64;                 // 2*N*64 interleaved
    bf16* wb  = kvb + 2 * N * 64;            // 49152
    bf16* sb  = wb + 49152;                  // N*64 (bf16)
    int* deg  = (int*)(sb + N * 64);         // N
    int* off  = deg + N_NODES;               // N+1
    int* gcur = off + N_NODES + 1;           // NBK*CURSTRIDE
    int* bsum = gcur + N_NODES;              // NB_SCAN
    int* boff = bsum + NB_SCAN;              // NB_SCAN+1 (unused now)
    unsigned short* csr = (unsigned short*)(boff + NB_SCAN + 1); // E u16 (in old int slot)
    unsigned int* pairs = (unsigned int*)((int*)csr + N_EDGES);  // E

    const int aggGrid = (N_NODES * 64 + 255) / 256;

    // ---------------- prep + CSR ----------------
    hipMemsetAsync(deg, 0, N_NODES * sizeof(int), stream);
    prep<<<dim3(1024, 3), 256, 0, stream>>>(x, xb, wp, wb, ei, deg);
    scan1<<<NB_SCAN, 256, 0, stream>>>(deg, off, bsum);
    scan3<<<NB_SCAN, 256, 0, stream>>>(off, bsum, gcur);

    // ---------------- Layer 1 (scatter-first + gemm fused) ----------------
    gemm1_scatter<<<GEMM_BLKS + SCAT_BLKS, 256, 0, stream>>>(
        xb, wb, bq1, bk1, bv1, bs1, qb, kvb, sb, ei, off, gcur, pairs);
    passB<<<NBK, 256, 0, stream>>>(off, pairs, csr);
    agg_csr<4, true, bf16><<<aggGrid, 256, 0, stream>>>(off, csr, qb,
                                                        (const unsigned int*)kvb, sb, hb);

    // ---------------- Layer 2 ----------------
    gemm2<<<GEMM_BLKS, 256, 0, stream>>>(hb, wb + 32768, bq2, bk2, bv2, bs2,
                                         qb, kvb, sb);
    agg_csr<1, false, float><<<aggGrid, 256, 0, stream>>>(off, csr, qb,
                                                          (const unsigned int*)kvb, sb,
                                                          (float*)d_out);
}

// Round 11
// 243.045 us; speedup vs baseline: 1.4143x; 1.1475x over previous
//
#include <hip/hip_runtime.h>
#include <hip/hip_bf16.h>

// ROUND 27. r26 NEUTRAL (278.9): scatter-first/scan-fold/u16 bought ~0.6us ->
// block ordering wasn't the issue; front-end chain is. This round deletes the
// CSR front-end: fixed CAP=6144 bucket windows in pairs (mean 4082, +32sigma,
// OOB-guarded) -> pass-A needs no off; deg-hist (800K atomics), memset, scan1,
// scan3 all deleted. passB derives off itself (bucket base = LDS prefix over
// gcur[0..b), node prefix via LDS scan) and writes off + ranked u16 csr.
// Chain: prep -> gemm1_scatter -> passB -> agg1 -> gemm2 -> agg2 (6 disp).
// Predict: total 278.9 -> ~262-270 (prep -6-10, gaps -6-9, passB +3-5).
// If neutral: remaining = fill + gather floor + gemm floor -> dot2 agg or stop.

#define N_NODES 50000
#define N_EDGES 800000
#define NPAD    50048 // allocation pad (>= 1563*32 = 50016)
#define GEMM_BLKS 1563 // ceil(50000/32), 32-row tiles
#define EPB 2048       // edges per scatter block
#define SCAT_BLKS 391  // ceil(800000/2048)
#define NBK 196        // buckets of 256 nodes (dst>>8)
#define CAP 6144       // fixed pairs window per bucket
#define CURSTRIDE 16   // one cursor per 64B line

using bf16 = __hip_bfloat16;
typedef __attribute__((ext_vector_type(8))) short bf16x8;
typedef __attribute__((ext_vector_type(4))) float f32x4;
typedef __attribute__((ext_vector_type(4))) unsigned int u32x4;
typedef __attribute__((ext_vector_type(2))) unsigned int u32x2;

__device__ __forceinline__ float b2f(unsigned short u) {
    unsigned int x = ((unsigned int)u) << 16;
    return __builtin_bit_cast(float, x);
}
__device__ __forceinline__ float lo_f(unsigned int u) {
    return __builtin_bit_cast(float, u << 16);
}
__device__ __forceinline__ float hi_f(unsigned int u) {
    return __builtin_bit_cast(float, u & 0xffff0000u);
}
__device__ __forceinline__ short f2b(float f) {
    return (short)__builtin_bit_cast(unsigned short, __float2bfloat16(f));
}

// DPP add helpers (verified on HW r24/r25).
template <int CTRL>
__device__ __forceinline__ float dadd(float p) {
    int vi = __builtin_bit_cast(int, p);
    int mv = __builtin_amdgcn_update_dpp(vi, vi, CTRL, 0xF, 0xF, false);
    return p + __builtin_bit_cast(float, mv);
}
template <int H>
__device__ __forceinline__ float edge_reduce(float p) {
    p = dadd<0xB1>(p);
    p = dadd<0x4E>(p);
    if constexpr (H == 1) {
        p = dadd<0x124>(p);  // row_ror:4
        p = dadd<0x128>(p);  // row_ror:8
    }
    return p;
}

struct WPtrs { const float* p[8]; };

// ---------------- fused prep: conv_x / (conv_w + gcur zero) ----------------
__global__ __launch_bounds__(256) void prep(const float* __restrict__ x,
                                            bf16* __restrict__ xb,
                                            WPtrs wp, bf16* __restrict__ wb,
                                            int* __restrict__ gcur) {
    const int gs = gridDim.x * 256;
    const int t0 = blockIdx.x * 256 + threadIdx.x;
    if (blockIdx.y == 0) {
        for (int i = t0; i < N_NODES * 16; i += gs) {
            const float* px = x + (size_t)i * 8;
            f32x4 v0 = *(const f32x4*)px;
            f32x4 v1 = *(const f32x4*)(px + 4);
            bf16x8 o;
#pragma unroll
            for (int q = 0; q < 4; ++q) {
                o[q]     = f2b(v0[q]);
                o[q + 4] = f2b(v1[q]);
            }
            *(bf16x8*)(xb + (size_t)i * 8) = o;
        }
    } else {
        if (t0 < NBK * CURSTRIDE) gcur[t0] = 0;
        for (int i = t0; i < 49152; i += gs) {
            int y, o;
            if (i < 32768) { y = i >> 13; o = i & 8191; }
            else { y = 4 + ((i - 32768) >> 12); o = (i - 32768) & 4095; }
            wb[i] = __float2bfloat16(wp.p[y][o]);
        }
    }
}

// ------------- MFMA GEMM body (MR*16-row tile, 4 weight mats) -------------
template <int K, int MR>
__device__ __forceinline__ void gemm_body(
    int blk, int tid,
    const bf16* __restrict__ A, const bf16* __restrict__ wb,
    const float* __restrict__ bq, const float* __restrict__ bk,
    const float* __restrict__ bv, const float* __restrict__ bs,
    bf16* __restrict__ qb, bf16* __restrict__ kvb, bf16* __restrict__ sb) {
    const int wave = tid >> 6;
    const int lane = tid & 63;
    const int row0 = blk * (MR * 16);
    const int m  = lane & 15;
    const int kg = lane >> 4;
    const bf16* W = wb + (size_t)wave * 64 * K;

    f32x4 acc[MR][4];
#pragma unroll
    for (int i = 0; i < MR; ++i)
#pragma unroll
        for (int j = 0; j < 4; ++j) acc[i][j] = (f32x4){0.f, 0.f, 0.f, 0.f};

#pragma unroll
    for (int k0 = 0; k0 < K; k0 += 32) {
        bf16x8 a[MR], b[4];
#pragma unroll
        for (int i = 0; i < MR; ++i)
            a[i] = *(const bf16x8*)(A + (size_t)(row0 + i * 16 + m) * K + k0 + kg * 8);
#pragma unroll
        for (int j = 0; j < 4; ++j)
            b[j] = *(const bf16x8*)(W + (size_t)(j * 16 + m) * K + k0 + kg * 8);
#pragma unroll
        for (int i = 0; i < MR; ++i)
#pragma unroll
            for (int j = 0; j < 4; ++j)
                acc[i][j] = __builtin_amdgcn_mfma_f32_16x16x32_bf16(a[i], b[j], acc[i][j], 0, 0, 0);
    }

    const int crow = (lane >> 4) * 4;
    const int ccol = lane & 15;
    const float* B = (wave == 0) ? bq : (wave == 1) ? bk : (wave == 2) ? bv : bs;
    float bias[4];
#pragma unroll
    for (int j = 0; j < 4; ++j) bias[j] = B[j * 16 + ccol];

#pragma unroll
    for (int i = 0; i < MR; ++i)
#pragma unroll
        for (int r = 0; r < 4; ++r) {
            int gr = row0 + i * 16 + crow + r;
            if (gr >= N_NODES) continue;
#pragma unroll
            for (int j = 0; j < 4; ++j) {
                float val = acc[i][j][r] + bias[j];
                size_t idx = (size_t)gr * 64 + j * 16 + ccol;
                if (wave == 0) qb[idx] = __float2bfloat16(val);
                else if (wave == 1) kvb[idx * 2] = __float2bfloat16(val);
                else if (wave == 2) kvb[idx * 2 + 1] = __float2bfloat16(val);
                else sb[idx] = __float2bfloat16(val);
            }
        }
}

// layer-1 GEMM + pass-A binning fused (scatter blocks first). Fixed-capacity
// bucket windows: obs = b*CAP + cursor -- no CSR offsets needed here.
__global__ __launch_bounds__(256) void gemm1_scatter(
    const bf16* __restrict__ A, const bf16* __restrict__ wb,
    const float* __restrict__ bq, const float* __restrict__ bk,
    const float* __restrict__ bv, const float* __restrict__ bs,
    bf16* __restrict__ qb, bf16* __restrict__ kvb, bf16* __restrict__ sb,
    const int* __restrict__ ei,
    int* __restrict__ gcur, unsigned int* __restrict__ pairs) {
    __shared__ int hist[256];
    __shared__ int sm[256];
    __shared__ int obs[NBK];
    __shared__ unsigned int stage[EPB];

    if (blockIdx.x >= SCAT_BLKS) {
        gemm_body<128, 2>(blockIdx.x - SCAT_BLKS, threadIdx.x, A, wb,
                          bq, bk, bv, bs, qb, kvb, sb);
        return;
    }
    const int t = threadIdx.x;
    const int e0 = blockIdx.x * EPB;
    hist[t] = 0;
    __syncthreads();

    unsigned int pk[8];
    int bb[8], rr[8];
#pragma unroll
    for (int u = 0; u < 8; ++u) {
        const int e = e0 + u * 256 + t;
        if (e < N_EDGES) {
            int d  = ei[N_EDGES + e];
            int sv = ei[e];
            pk[u] = ((unsigned int)d << 16) | (unsigned int)sv;
            bb[u] = d >> 8;
            rr[u] = atomicAdd(&hist[bb[u]], 1);
        } else {
            bb[u] = -1;
        }
    }
    __syncthreads();

    int hv = hist[t];
    sm[t] = hv;
    __syncthreads();
    for (int st = 1; st < 256; st <<= 1) {
        int tmp = (t >= st) ? sm[t - st] : 0;
        __syncthreads();
        sm[t] += tmp;
        __syncthreads();
    }
    const int total = sm[255];

    // one global reservation per non-empty bucket; window base = t*CAP
    if (t < NBK && hv > 0) {
        int g = atomicAdd(&gcur[t * CURSTRIDE], hv);
        obs[t] = t * CAP + g - (sm[t] - hv);
    }
    __syncthreads();

#pragma unroll
    for (int u = 0; u < 8; ++u)
        if (bb[u] >= 0) stage[(sm[bb[u]] - hist[bb[u]]) + rr[u]] = pk[u];
    __syncthreads();

    for (int j = t; j < total; j += 256) {
        unsigned int pr = stage[j];
        int b = pr >> 24;  // dst>>8 (dst < 65536)
        int pos = obs[b] + j;
        if (pos - b * CAP < CAP)  // overflow guard (deterministic input: no-op)
            pairs[pos] = pr;
    }
}

// Pass B: one block per bucket. Derives bucket base (prefix over gcur),
// per-node offsets (LDS count+scan), writes off[] and ranked u16 csr.
__global__ __launch_bounds__(256) void passB(const int* __restrict__ gcur,
                                             const unsigned int* __restrict__ pairs,
                                             unsigned short* __restrict__ csr,
                                             int* __restrict__ off) {
    __shared__ int bsm[256];
    __shared__ int cnt[256];
    __shared__ int pfx[256];
    __shared__ int place[256];
    const int b = blockIdx.x;
    const int t = threadIdx.x;
    const int n0 = b << 8;
    const int nb = ((n0 + 256 < N_NODES) ? 256 : N_NODES - n0);

    // bucket base = sum of gcur[0..b)
    int gv = (t < NBK) ? gcur[t * CURSTRIDE] : 0;
    bsm[t] = (t < b) ? gv : 0;
    cnt[t] = 0;
    place[t] = 0;
    __syncthreads();
    for (int st = 128; st >= 1; st >>= 1) {
        if (t < st) bsm[t] += bsm[t + st];
        __syncthreads();
    }
    const int base = bsm[0];
    const int myCnt = gcur[b * CURSTRIDE];
    const unsigned int* win = pairs + (size_t)b * CAP;

    // count per node
    for (int j = t; j < myCnt; j += 256)
        atomicAdd(&cnt[(win[j] >> 16) - n0], 1);
    __syncthreads();

    // inclusive scan -> exclusive prefix
    int cv = cnt[t];
    pfx[t] = cv;
    __syncthreads();
    for (int st = 1; st < 256; st <<= 1) {
        int tmp = (t >= st) ? pfx[t - st] : 0;
        __syncthreads();
        pfx[t] += tmp;
        __syncthreads();
    }
    const int excl = pfx[t] - cv;

    if (t < nb) off[n0 + t] = base + excl;
    if (b == NBK - 1 && t == 0) off[N_NODES] = base + myCnt;

    // rank and place (dense stores within the bucket's contiguous csr region)
    for (int j = t; j < myCnt; j += 256) {
        unsigned int pr = win[j];
        int i = (int)(pr >> 16) - n0;
        int r = atomicAdd(&place[i], 1);
        csr[base + (pfx[i] - cnt[i]) + r] = (unsigned short)(pr & 0xffffu);
    }
}

__global__ __launch_bounds__(256) void gemm2(
    const bf16* __restrict__ A, const bf16* __restrict__ wb,
    const float* __restrict__ bq, const float* __restrict__ bk,
    const float* __restrict__ bv, const float* __restrict__ bs,
    bf16* __restrict__ qb, bf16* __restrict__ kvb, bf16* __restrict__ sb) {
    gemm_body<64, 2>(blockIdx.x, threadIdx.x, A, wb, bq, bk, bv, bs, qb, kvb, sb);
}

// ---- Aggregation: 4 edge-slots/wave, 16 lanes/slot, 4 dims/lane ----
template <int H, bool RELU, typename OT>
__global__ __launch_bounds__(256) void agg_csr(const int* __restrict__ off,
                                               const unsigned short* __restrict__ csr_src,
                                               const bf16* __restrict__ qb,
                                               const unsigned int* __restrict__ kvu,
                                               const bf16* __restrict__ sb,
                                               OT* __restrict__ out) {
    const float SC = ((H == 4) ? 0.25f : 0.125f) * 1.4426950408889634f;
    const int lane = threadIdx.x & 63;
    const int slot = lane >> 4;
    const int m    = lane & 15;
    const int n = (blockIdx.x * 256 + threadIdx.x) >> 6;
    if (n >= N_NODES) return;

    const unsigned int* qp = (const unsigned int*)qb + (size_t)n * 32 + m * 2;
    const unsigned int q01 = qp[0], q23 = qp[1];
    const float qf0 = lo_f(q01), qf1 = hi_f(q01);
    const float qf2 = lo_f(q23), qf3 = hi_f(q23);

    float a0 = 0.f, a1 = 0.f, a2 = 0.f, a3 = 0.f, ds = 0.f;
    int jb = off[n];
    const int j1 = off[n + 1];
    const unsigned int mb = (unsigned)m * 4;

    for (; jb + 8 <= j1; jb += 8) {
        const unsigned s0 = (unsigned)csr_src[jb + slot];
        const unsigned s1 = (unsigned)csr_src[jb + 4 + slot];
        u32x4 w0 = *(const u32x4*)(kvu + (((size_t)s0) << 6) + mb);
        u32x4 w1 = *(const u32x4*)(kvu + (((size_t)s1) << 6) + mb);
        float p0 = qf0 * lo_f(w0[0]);
        p0 = fmaf(qf1, lo_f(w0[1]), p0);
        p0 = fmaf(qf2, lo_f(w0[2]), p0);
        p0 = fmaf(qf3, lo_f(w0[3]), p0);
        float p1 = qf0 * lo_f(w1[0]);
        p1 = fmaf(qf1, lo_f(w1[1]), p1);
        p1 = fmaf(qf2, lo_f(w1[2]), p1);
        p1 = fmaf(qf3, lo_f(w1[3]), p1);
        p0 = edge_reduce<H>(p0);
        p1 = edge_reduce<H>(p1);
        const float e0 = exp2f(p0 * SC);
        const float e1 = exp2f(p1 * SC);
        a0 = fmaf(e0, hi_f(w0[0]), a0); a0 = fmaf(e1, hi_f(w1[0]), a0);
        a1 = fmaf(e0, hi_f(w0[1]), a1); a1 = fmaf(e1, hi_f(w1[1]), a1);
        a2 = fmaf(e0, hi_f(w0[2]), a2); a2 = fmaf(e1, hi_f(w1[2]), a2);
        a3 = fmaf(e0, hi_f(w0[3]), a3); a3 = fmaf(e1, hi_f(w1[3]), a3);
        ds += e0 + e1;
    }
    for (; jb < j1; jb += 4) {
        int jc = jb + slot;
        const bool valid = jc < j1;
        if (!valid) jc = j1 - 1;
        const unsigned s0 = (unsigned)csr_src[jc];
        u32x4 w0 = *(const u32x4*)(kvu + (((size_t)s0) << 6) + mb);
        float p0 = qf0 * lo_f(w0[0]);
        p0 = fmaf(qf1, lo_f(w0[1]), p0);
        p0 = fmaf(qf2, lo_f(w0[2]), p0);
        p0 = fmaf(qf3, lo_f(w0[3]), p0);
        p0 = edge_reduce<H>(p0);
        const float e0 = valid ? exp2f(p0 * SC) : 0.f;
        a0 = fmaf(e0, hi_f(w0[0]), a0);
        a1 = fmaf(e0, hi_f(w0[1]), a1);
        a2 = fmaf(e0, hi_f(w0[2]), a2);
        a3 = fmaf(e0, hi_f(w0[3]), a3);
        ds += e0;
    }

    a0 += __shfl_xor(a0, 16, 64); a0 += __shfl_xor(a0, 32, 64);
    a1 += __shfl_xor(a1, 16, 64); a1 += __shfl_xor(a1, 32, 64);
    a2 += __shfl_xor(a2, 16, 64); a2 += __shfl_xor(a2, 32, 64);
    a3 += __shfl_xor(a3, 16, 64); a3 += __shfl_xor(a3, 32, 64);
    ds += __shfl_xor(ds, 16, 64); ds += __shfl_xor(ds, 32, 64);

    if (lane < 16) {
        const float inv = (ds != 0.f) ? 1.f / ds : 0.f;
        const unsigned int* sp = (const unsigned int*)sb + (size_t)n * 32 + m * 2;
        const unsigned int s01 = sp[0], s23 = sp[1];
        float v0 = fmaf(a0, inv, lo_f(s01));
        float v1 = fmaf(a1, inv, hi_f(s01));
        float v2 = fmaf(a2, inv, lo_f(s23));
        float v3 = fmaf(a3, inv, hi_f(s23));
        if (RELU) {
            v0 = fmaxf(v0, 0.f); v1 = fmaxf(v1, 0.f);
            v2 = fmaxf(v2, 0.f); v3 = fmaxf(v3, 0.f);
        }
        if constexpr (__hip_internal::is_same<OT, bf16>::value) {
            u32x2 o;
            o[0] = (unsigned)(unsigned short)f2b(v0) |
                   ((unsigned)(unsigned short)f2b(v1) << 16);
            o[1] = (unsigned)(unsigned short)f2b(v2) |
                   ((unsigned)(unsigned short)f2b(v3) << 16);
            *(u32x2*)((unsigned int*)out + (size_t)n * 32 + m * 2) = o;  // hb
        } else {
            f32x4 o = (f32x4){v0, v1, v2, v3};
            __builtin_nontemporal_store(o, (f32x4*)((float*)out + (size_t)n * 64 + mb));
        }
    }
}

extern "C" void kernel_launch(void* const* d_in, const int* in_sizes, int n_in,
                              void* d_out, int out_size, void* d_ws, size_t ws_size,
                              hipStream_t stream) {
    const float* x  = (const float*)d_in[0];
    const int*   ei = (const int*)d_in[1];
    const float* bq1 = (const float*)d_in[3];
    const float* bk1 = (const float*)d_in[5];
    const float* bv1 = (const float*)d_in[7];
    const float* bs1 = (const float*)d_in[9];
    const float* bq2 = (const float*)d_in[11];
    const float* bk2 = (const float*)d_in[13];
    const float* bv2 = (const float*)d_in[15];
    const float* bs2 = (const float*)d_in[17];

    WPtrs wp;
    wp.p[0] = (const float*)d_in[2];
    wp.p[1] = (const float*)d_in[4];
    wp.p[2] = (const float*)d_in[6];
    wp.p[3] = (const float*)d_in[8];
    wp.p[4] = (const float*)d_in[10];
    wp.p[5] = (const float*)d_in[12];
    wp.p[6] = (const float*)d_in[14];
    wp.p[7] = (const float*)d_in[16];

    const size_t N = N_NODES;
    bf16* xb  = (bf16*)d_ws;                 // NPAD*128
    bf16* hb  = xb + (size_t)NPAD * 128;     // NPAD*64
    bf16* qb  = hb + (size_t)NPAD * 64;      // N*64
    bf16* kvb = qb + N * 64;                 // 2*N*64 interleaved
    bf16* wb  = kvb + 2 * N * 64;            // 49152
    bf16* sb  = wb + 49152;                  // N*64 (bf16)
    int* off  = (int*)(sb + N * 64);         // N+1
    int* gcur = off + N_NODES + 1;           // NBK*CURSTRIDE
    unsigned short* csr = (unsigned short*)(gcur + NBK * CURSTRIDE); // E u16
    unsigned int* pairs = (unsigned int*)(csr + N_EDGES);            // NBK*CAP

    const int aggGrid = (N_NODES * 64 + 255) / 256;

    // ---------------- prep (x-conv, w-conv + gcur zero) ----------------
    prep<<<dim3(1024, 2), 256, 0, stream>>>(x, xb, wp, wb, gcur);

    // ---------------- Layer 1 (scatter-first + gemm fused) ----------------
    gemm1_scatter<<<GEMM_BLKS + SCAT_BLKS, 256, 0, stream>>>(
        xb, wb, bq1, bk1, bv1, bs1, qb, kvb, sb, ei, gcur, pairs);
    passB<<<NBK, 256, 0, stream>>>(gcur, pairs, csr, off);
    agg_csr<4, true, bf16><<<aggGrid, 256, 0, stream>>>(off, csr, qb,
                                                        (const unsigned int*)kvb, sb, hb);

    // ---------------- Layer 2 ----------------
    gemm2<<<GEMM_BLKS, 256, 0, stream>>>(hb, wb + 32768, bq2, bk2, bv2, bs2,
                                         qb, kvb, sb);
    agg_csr<1, false, float><<<aggGrid, 256, 0, stream>>>(off, csr, qb,
                                                          (const unsigned int*)kvb, sb,
                                                          (float*)d_out);
}

// Round 12
// 238.228 us; speedup vs baseline: 1.4429x; 1.0202x over previous
//
#include <hip/hip_runtime.h>
#include <hip/hip_bf16.h>

// ROUND 28. r27 WIN (243.0, -36us): front-end deletion over-delivered --
// serial small-dispatch chains cost more than counter-visible time.
// Budget: 243 - 44 fill = 199us: prep ~9 (x-conv 38.4MB), gemm1_scatter ~50,
// passB ~10, agg ~38x2, gemm2 ~18, gaps ~10.
// Changes:
//  1) x-conv deleted from prep; gemm1 blocks stage their 32 f32 x-rows into
//     LDS (cvt once, 132-stride pad, 8B ops conflict-free), MFMA reads LDS.
//     Fixes r21's failure mode (loads no longer on MFMA dependent chain).
//     Net: -38.4MB traffic + ~7us serial prep, +12.8MB f32 reads in gemm1.
//  2) passB reads its window ONCE into regs (<=24 pairs/thread), was 2x
//     global read. 196-block latency-bound kernel -> outsized effect.
// Predict: 243 -> ~233-238. If <4us gain: fill+gather+gemm floor -> fp8-k
// experiment or structural stop.

#define N_NODES 50000
#define N_EDGES 800000
#define NPAD    50048
#define GEMM_BLKS 1563 // ceil(50000/32), 32-row tiles
#define EPB 2048       // edges per scatter block
#define SCAT_BLKS 391  // ceil(800000/2048)
#define NBK 196        // buckets of 256 nodes (dst>>8)
#define CAP 6144       // fixed pairs window per bucket
#define CAPT 24        // CAP/256 per-thread reg hold in passB
#define CURSTRIDE 16   // one cursor per 64B line
#define ALDS 132       // padded LDS row stride (bf16 units)

using bf16 = __hip_bfloat16;
typedef __attribute__((ext_vector_type(8))) short bf16x8;
typedef __attribute__((ext_vector_type(4))) short bf16x4;
typedef __attribute__((ext_vector_type(4))) float f32x4;
typedef __attribute__((ext_vector_type(4))) unsigned int u32x4;
typedef __attribute__((ext_vector_type(2))) unsigned int u32x2;

__device__ __forceinline__ float b2f(unsigned short u) {
    unsigned int x = ((unsigned int)u) << 16;
    return __builtin_bit_cast(float, x);
}
__device__ __forceinline__ float lo_f(unsigned int u) {
    return __builtin_bit_cast(float, u << 16);
}
__device__ __forceinline__ float hi_f(unsigned int u) {
    return __builtin_bit_cast(float, u & 0xffff0000u);
}
__device__ __forceinline__ short f2b(float f) {
    return (short)__builtin_bit_cast(unsigned short, __float2bfloat16(f));
}

// DPP add helpers (verified on HW r24/r25).
template <int CTRL>
__device__ __forceinline__ float dadd(float p) {
    int vi = __builtin_bit_cast(int, p);
    int mv = __builtin_amdgcn_update_dpp(vi, vi, CTRL, 0xF, 0xF, false);
    return p + __builtin_bit_cast(float, mv);
}
template <int H>
__device__ __forceinline__ float edge_reduce(float p) {
    p = dadd<0xB1>(p);
    p = dadd<0x4E>(p);
    if constexpr (H == 1) {
        p = dadd<0x124>(p);  // row_ror:4
        p = dadd<0x128>(p);  // row_ror:8
    }
    return p;
}

struct WPtrs { const float* p[8]; };

// ---------------- prep: conv_w + gcur zero (tiny now) ----------------
__global__ __launch_bounds__(256) void prep(WPtrs wp, bf16* __restrict__ wb,
                                            int* __restrict__ gcur) {
    const int gs = gridDim.x * 256;
    const int t0 = blockIdx.x * 256 + threadIdx.x;
    if (t0 < NBK * CURSTRIDE) gcur[t0] = 0;
    for (int i = t0; i < 49152; i += gs) {
        int y, o;
        if (i < 32768) { y = i >> 13; o = i & 8191; }
        else { y = 4 + ((i - 32768) >> 12); o = (i - 32768) & 4095; }
        wb[i] = __float2bfloat16(wp.p[y][o]);
    }
}

// ------------- MFMA GEMM body (32-row tile, 4 weight mats) -------------
// LDSA: A points to LDS (stride ALDS, local rows). else global (stride K).
template <int K, bool LDSA>
__device__ __forceinline__ void gemm_body(
    int blk, int tid,
    const bf16* __restrict__ A, const bf16* __restrict__ wb,
    const float* __restrict__ bq, const float* __restrict__ bk,
    const float* __restrict__ bv, const float* __restrict__ bs,
    bf16* __restrict__ qb, bf16* __restrict__ kvb, bf16* __restrict__ sb) {
    const int wave = tid >> 6;
    const int lane = tid & 63;
    const int row0 = blk * 32;
    const int m  = lane & 15;
    const int kg = lane >> 4;
    const bf16* W = wb + (size_t)wave * 64 * K;

    f32x4 acc[2][4];
#pragma unroll
    for (int i = 0; i < 2; ++i)
#pragma unroll
        for (int j = 0; j < 4; ++j) acc[i][j] = (f32x4){0.f, 0.f, 0.f, 0.f};

#pragma unroll
    for (int k0 = 0; k0 < K; k0 += 32) {
        bf16x8 a[2], b[4];
#pragma unroll
        for (int i = 0; i < 2; ++i) {
            if constexpr (LDSA) {
                const bf16* ap = A + (size_t)(i * 16 + m) * ALDS + k0 + kg * 8;
                bf16x4 lo = *(const bf16x4*)ap;
                bf16x4 hi = *(const bf16x4*)(ap + 4);
#pragma unroll
                for (int q = 0; q < 4; ++q) { a[i][q] = lo[q]; a[i][q + 4] = hi[q]; }
            } else {
                a[i] = *(const bf16x8*)(A + (size_t)(row0 + i * 16 + m) * K + k0 + kg * 8);
            }
        }
#pragma unroll
        for (int j = 0; j < 4; ++j)
            b[j] = *(const bf16x8*)(W + (size_t)(j * 16 + m) * K + k0 + kg * 8);
#pragma unroll
        for (int i = 0; i < 2; ++i)
#pragma unroll
            for (int j = 0; j < 4; ++j)
                acc[i][j] = __builtin_amdgcn_mfma_f32_16x16x32_bf16(a[i], b[j], acc[i][j], 0, 0, 0);
    }

    const int crow = (lane >> 4) * 4;
    const int ccol = lane & 15;
    const float* B = (wave == 0) ? bq : (wave == 1) ? bk : (wave == 2) ? bv : bs;
    float bias[4];
#pragma unroll
    for (int j = 0; j < 4; ++j) bias[j] = B[j * 16 + ccol];

#pragma unroll
    for (int i = 0; i < 2; ++i)
#pragma unroll
        for (int r = 0; r < 4; ++r) {
            int gr = row0 + i * 16 + crow + r;
            if (gr >= N_NODES) continue;
#pragma unroll
            for (int j = 0; j < 4; ++j) {
                float val = acc[i][j][r] + bias[j];
                size_t idx = (size_t)gr * 64 + j * 16 + ccol;
                if (wave == 0) qb[idx] = __float2bfloat16(val);
                else if (wave == 1) kvb[idx * 2] = __float2bfloat16(val);
                else if (wave == 2) kvb[idx * 2 + 1] = __float2bfloat16(val);
                else sb[idx] = __float2bfloat16(val);
            }
        }
}

// layer-1: scatter blocks first, then gemm blocks (f32 x staged via LDS).
__global__ __launch_bounds__(256) void gemm1_scatter(
    const float* __restrict__ x, const bf16* __restrict__ wb,
    const float* __restrict__ bq, const float* __restrict__ bk,
    const float* __restrict__ bv, const float* __restrict__ bs,
    bf16* __restrict__ qb, bf16* __restrict__ kvb, bf16* __restrict__ sb,
    const int* __restrict__ ei,
    int* __restrict__ gcur, unsigned int* __restrict__ pairs) {
    __shared__ union {
        struct {
            int hist[256];
            int sm[256];
            int obs[NBK];
            unsigned int stage[EPB];
        } s;
        bf16 As[32 * ALDS];
    } u;

    const int t = threadIdx.x;

    if (blockIdx.x >= SCAT_BLKS) {
        const int blk = blockIdx.x - SCAT_BLKS;
        const int row0 = blk * 32;
        // stage 32 f32 rows -> bf16 LDS (thread t: row t>>3, cols (t&7)*16..+15)
        {
            const int r = t >> 3;
            const int c0 = (t & 7) << 4;
            int gr = row0 + r;
            if (gr >= N_NODES) gr = N_NODES - 1;
            const float* px = x + (size_t)gr * 128 + c0;
            f32x4 v0 = *(const f32x4*)px;
            f32x4 v1 = *(const f32x4*)(px + 4);
            f32x4 v2 = *(const f32x4*)(px + 8);
            f32x4 v3 = *(const f32x4*)(px + 12);
            bf16* dst = u.As + r * ALDS + c0;
            bf16x4 o0 = {f2b(v0[0]), f2b(v0[1]), f2b(v0[2]), f2b(v0[3])};
            bf16x4 o1 = {f2b(v1[0]), f2b(v1[1]), f2b(v1[2]), f2b(v1[3])};
            bf16x4 o2 = {f2b(v2[0]), f2b(v2[1]), f2b(v2[2]), f2b(v2[3])};
            bf16x4 o3 = {f2b(v3[0]), f2b(v3[1]), f2b(v3[2]), f2b(v3[3])};
            *(bf16x4*)(dst)     = o0;
            *(bf16x4*)(dst + 4) = o1;
            *(bf16x4*)(dst + 8) = o2;
            *(bf16x4*)(dst + 12) = o3;
        }
        __syncthreads();
        gemm_body<128, true>(blk, t, u.As, wb, bq, bk, bv, bs, qb, kvb, sb);
        return;
    }

    const int e0 = blockIdx.x * EPB;
    u.s.hist[t] = 0;
    __syncthreads();

    unsigned int pk[8];
    int bb[8], rr[8];
#pragma unroll
    for (int uu = 0; uu < 8; ++uu) {
        const int e = e0 + uu * 256 + t;
        if (e < N_EDGES) {
            int d  = ei[N_EDGES + e];
            int sv = ei[e];
            pk[uu] = ((unsigned int)d << 16) | (unsigned int)sv;
            bb[uu] = d >> 8;
            rr[uu] = atomicAdd(&u.s.hist[bb[uu]], 1);
        } else {
            bb[uu] = -1;
        }
    }
    __syncthreads();

    int hv = u.s.hist[t];
    u.s.sm[t] = hv;
    __syncthreads();
    for (int st = 1; st < 256; st <<= 1) {
        int tmp = (t >= st) ? u.s.sm[t - st] : 0;
        __syncthreads();
        u.s.sm[t] += tmp;
        __syncthreads();
    }
    const int total = u.s.sm[255];

    if (t < NBK && hv > 0) {
        int g = atomicAdd(&gcur[t * CURSTRIDE], hv);
        u.s.obs[t] = t * CAP + g - (u.s.sm[t] - hv);
    }
    __syncthreads();

#pragma unroll
    for (int uu = 0; uu < 8; ++uu)
        if (bb[uu] >= 0)
            u.s.stage[(u.s.sm[bb[uu]] - u.s.hist[bb[uu]]) + rr[uu]] = pk[uu];
    __syncthreads();

    for (int j = t; j < total; j += 256) {
        unsigned int pr = u.s.stage[j];
        int b = pr >> 24;
        int pos = u.s.obs[b] + j;
        if (pos - b * CAP < CAP)
            pairs[pos] = pr;
    }
}

// Pass B: one block per bucket; single window read into registers.
__global__ __launch_bounds__(256) void passB(const int* __restrict__ gcur,
                                             const unsigned int* __restrict__ pairs,
                                             unsigned short* __restrict__ csr,
                                             int* __restrict__ off) {
    __shared__ int bsm[256];
    __shared__ int cnt[256];
    __shared__ int pfx[256];
    __shared__ int place[256];
    const int b = blockIdx.x;
    const int t = threadIdx.x;
    const int n0 = b << 8;
    const int nb = ((n0 + 256 < N_NODES) ? 256 : N_NODES - n0);

    int gv = (t < NBK) ? gcur[t * CURSTRIDE] : 0;
    bsm[t] = (t < b) ? gv : 0;
    cnt[t] = 0;
    place[t] = 0;
    __syncthreads();
    for (int st = 128; st >= 1; st >>= 1) {
        if (t < st) bsm[t] += bsm[t + st];
        __syncthreads();
    }
    const int base = bsm[0];
    const int myCnt = gcur[b * CURSTRIDE];
    const unsigned int* win = pairs + (size_t)b * CAP;

    // single global read of the window into registers
    unsigned int pr[CAPT];
    int held = 0;
    for (int j = t; j < myCnt; j += 256) pr[held++] = win[j];

    for (int k = 0; k < held; ++k)
        atomicAdd(&cnt[(pr[k] >> 16) - n0], 1);
    __syncthreads();

    int cv = cnt[t];
    pfx[t] = cv;
    __syncthreads();
    for (int st = 1; st < 256; st <<= 1) {
        int tmp = (t >= st) ? pfx[t - st] : 0;
        __syncthreads();
        pfx[t] += tmp;
        __syncthreads();
    }
    const int excl = pfx[t] - cv;

    if (t < nb) off[n0 + t] = base + excl;
    if (b == NBK - 1 && t == 0) off[N_NODES] = base + myCnt;

    for (int k = 0; k < held; ++k) {
        unsigned int p = pr[k];
        int i = (int)(p >> 16) - n0;
        int r = atomicAdd(&place[i], 1);
        csr[base + (pfx[i] - cnt[i]) + r] = (unsigned short)(p & 0xffffu);
    }
}

__global__ __launch_bounds__(256) void gemm2(
    const bf16* __restrict__ A, const bf16* __restrict__ wb,
    const float* __restrict__ bq, const float* __restrict__ bk,
    const float* __restrict__ bv, const float* __restrict__ bs,
    bf16* __restrict__ qb, bf16* __restrict__ kvb, bf16* __restrict__ sb) {
    gemm_body<64, false>(blockIdx.x, threadIdx.x, A, wb, bq, bk, bv, bs, qb, kvb, sb);
}

// ---- Aggregation: 4 edge-slots/wave, 16 lanes/slot, 4 dims/lane ----
template <int H, bool RELU, typename OT>
__global__ __launch_bounds__(256) void agg_csr(const int* __restrict__ off,
                                               const unsigned short* __restrict__ csr_src,
                                               const bf16* __restrict__ qb,
                                               const unsigned int* __restrict__ kvu,
                                               const bf16* __restrict__ sb,
                                               OT* __restrict__ out) {
    const float SC = ((H == 4) ? 0.25f : 0.125f) * 1.4426950408889634f;
    const int lane = threadIdx.x & 63;
    const int slot = lane >> 4;
    const int m    = lane & 15;
    const int n = (blockIdx.x * 256 + threadIdx.x) >> 6;
    if (n >= N_NODES) return;

    const unsigned int* qp = (const unsigned int*)qb + (size_t)n * 32 + m * 2;
    const unsigned int q01 = qp[0], q23 = qp[1];
    const float qf0 = lo_f(q01), qf1 = hi_f(q01);
    const float qf2 = lo_f(q23), qf3 = hi_f(q23);

    float a0 = 0.f, a1 = 0.f, a2 = 0.f, a3 = 0.f, ds = 0.f;
    int jb = off[n];
    const int j1 = off[n + 1];
    const unsigned int mb = (unsigned)m * 4;

    for (; jb + 8 <= j1; jb += 8) {
        const unsigned s0 = (unsigned)csr_src[jb + slot];
        const unsigned s1 = (unsigned)csr_src[jb + 4 + slot];
        u32x4 w0 = *(const u32x4*)(kvu + (((size_t)s0) << 6) + mb);
        u32x4 w1 = *(const u32x4*)(kvu + (((size_t)s1) << 6) + mb);
        float p0 = qf0 * lo_f(w0[0]);
        p0 = fmaf(qf1, lo_f(w0[1]), p0);
        p0 = fmaf(qf2, lo_f(w0[2]), p0);
        p0 = fmaf(qf3, lo_f(w0[3]), p0);
        float p1 = qf0 * lo_f(w1[0]);
        p1 = fmaf(qf1, lo_f(w1[1]), p1);
        p1 = fmaf(qf2, lo_f(w1[2]), p1);
        p1 = fmaf(qf3, lo_f(w1[3]), p1);
        p0 = edge_reduce<H>(p0);
        p1 = edge_reduce<H>(p1);
        const float e0 = exp2f(p0 * SC);
        const float e1 = exp2f(p1 * SC);
        a0 = fmaf(e0, hi_f(w0[0]), a0); a0 = fmaf(e1, hi_f(w1[0]), a0);
        a1 = fmaf(e0, hi_f(w0[1]), a1); a1 = fmaf(e1, hi_f(w1[1]), a1);
        a2 = fmaf(e0, hi_f(w0[2]), a2); a2 = fmaf(e1, hi_f(w1[2]), a2);
        a3 = fmaf(e0, hi_f(w0[3]), a3); a3 = fmaf(e1, hi_f(w1[3]), a3);
        ds += e0 + e1;
    }
    for (; jb < j1; jb += 4) {
        int jc = jb + slot;
        const bool valid = jc < j1;
        if (!valid) jc = j1 - 1;
        const unsigned s0 = (unsigned)csr_src[jc];
        u32x4 w0 = *(const u32x4*)(kvu + (((size_t)s0) << 6) + mb);
        float p0 = qf0 * lo_f(w0[0]);
        p0 = fmaf(qf1, lo_f(w0[1]), p0);
        p0 = fmaf(qf2, lo_f(w0[2]), p0);
        p0 = fmaf(qf3, lo_f(w0[3]), p0);
        p0 = edge_reduce<H>(p0);
        const float e0 = valid ? exp2f(p0 * SC) : 0.f;
        a0 = fmaf(e0, hi_f(w0[0]), a0);
        a1 = fmaf(e0, hi_f(w0[1]), a1);
        a2 = fmaf(e0, hi_f(w0[2]), a2);
        a3 = fmaf(e0, hi_f(w0[3]), a3);
        ds += e0;
    }

    a0 += __shfl_xor(a0, 16, 64); a0 += __shfl_xor(a0, 32, 64);
    a1 += __shfl_xor(a1, 16, 64); a1 += __shfl_xor(a1, 32, 64);
    a2 += __shfl_xor(a2, 16, 64); a2 += __shfl_xor(a2, 32, 64);
    a3 += __shfl_xor(a3, 16, 64); a3 += __shfl_xor(a3, 32, 64);
    ds += __shfl_xor(ds, 16, 64); ds += __shfl_xor(ds, 32, 64);

    if (lane < 16) {
        const float inv = (ds != 0.f) ? 1.f / ds : 0.f;
        const unsigned int* sp = (const unsigned int*)sb + (size_t)n * 32 + m * 2;
        const unsigned int s01 = sp[0], s23 = sp[1];
        float v0 = fmaf(a0, inv, lo_f(s01));
        float v1 = fmaf(a1, inv, hi_f(s01));
        float v2 = fmaf(a2, inv, lo_f(s23));
        float v3 = fmaf(a3, inv, hi_f(s23));
        if (RELU) {
            v0 = fmaxf(v0, 0.f); v1 = fmaxf(v1, 0.f);
            v2 = fmaxf(v2, 0.f); v3 = fmaxf(v3, 0.f);
        }
        if constexpr (__hip_internal::is_same<OT, bf16>::value) {
            u32x2 o;
            o[0] = (unsigned)(unsigned short)f2b(v0) |
                   ((unsigned)(unsigned short)f2b(v1) << 16);
            o[1] = (unsigned)(unsigned short)f2b(v2) |
                   ((unsigned)(unsigned short)f2b(v3) << 16);
            *(u32x2*)((unsigned int*)out + (size_t)n * 32 + m * 2) = o;  // hb
        } else {
            f32x4 o = (f32x4){v0, v1, v2, v3};
            __builtin_nontemporal_store(o, (f32x4*)((float*)out + (size_t)n * 64 + mb));
        }
    }
}

extern "C" void kernel_launch(void* const* d_in, const int* in_sizes, int n_in,
                              void* d_out, int out_size, void* d_ws, size_t ws_size,
                              hipStream_t stream) {
    const float* x  = (const float*)d_in[0];
    const int*   ei = (const int*)d_in[1];
    const float* bq1 = (const float*)d_in[3];
    const float* bk1 = (const float*)d_in[5];
    const float* bv1 = (const float*)d_in[7];
    const float* bs1 = (const float*)d_in[9];
    const float* bq2 = (const float*)d_in[11];
    const float* bk2 = (const float*)d_in[13];
    const float* bv2 = (const float*)d_in[15];
    const float* bs2 = (const float*)d_in[17];

    WPtrs wp;
    wp.p[0] = (const float*)d_in[2];
    wp.p[1] = (const float*)d_in[4];
    wp.p[2] = (const float*)d_in[6];
    wp.p[3] = (const float*)d_in[8];
    wp.p[4] = (const float*)d_in[10];
    wp.p[5] = (const float*)d_in[12];
    wp.p[6] = (const float*)d_in[14];
    wp.p[7] = (const float*)d_in[16];

    const size_t N = N_NODES;
    bf16* hb  = (bf16*)d_ws;                 // NPAD*64
    bf16* qb  = hb + (size_t)NPAD * 64;      // N*64
    bf16* kvb = qb + N * 64;                 // 2*N*64 interleaved
    bf16* wb  = kvb + 2 * N * 64;            // 49152
    bf16* sb  = wb + 49152;                  // N*64 (bf16)
    int* off  = (int*)(sb + N * 64);         // N+1
    int* gcur = off + N_NODES + 1;           // NBK*CURSTRIDE
    unsigned short* csr = (unsigned short*)(gcur + NBK * CURSTRIDE); // E u16
    unsigned int* pairs = (unsigned int*)(csr + N_EDGES);            // NBK*CAP

    const int aggGrid = (N_NODES * 64 + 255) / 256;

    // ---------------- prep (w-conv + gcur zero; tiny) ----------------
    prep<<<64, 256, 0, stream>>>(wp, wb, gcur);

    // ---------------- Layer 1 (scatter-first + gemm w/ LDS-staged x) -------
    gemm1_scatter<<<GEMM_BLKS + SCAT_BLKS, 256, 0, stream>>>(
        x, wb, bq1, bk1, bv1, bs1, qb, kvb, sb, ei, gcur, pairs);
    passB<<<NBK, 256, 0, stream>>>(gcur, pairs, csr, off);
    agg_csr<4, true, bf16><<<aggGrid, 256, 0, stream>>>(off, csr, qb,
                                                        (const unsigned int*)kvb, sb, hb);

    // ---------------- Layer 2 ----------------
    gemm2<<<GEMM_BLKS, 256, 0, stream>>>(hb, wb + 32768, bq2, bk2, bv2, bs2,
                                         qb, kvb, sb);
    agg_csr<1, false, float><<<aggGrid, 256, 0, stream>>>(off, csr, qb,
                                                          (const unsigned int*)kvb, sb,
                                                          (float*)d_out);
}